// Round 1
// baseline (405.710 us; speedup 1.0000x reference)
//
#include <hip/hip_runtime.h>
#include <hip/hip_bf16.h>
#include <math.h>

#define B_ 8
#define N_ 1024
#define H_ 14
#define DH_ 64
#define D_ 896
#define M_ (B_*N_)        // 8192 rows
#define DQKV_ 2688        // 3*D_

// exp2-domain constants: log2(e), 2*log2(e), log2(e)*(1 - M0) with M0 = 12
#define TWO_LOG2E_ 2.8853900817779268f
#define BIAS_C_   (-15.869645449778597f)
#define QSCALE_     0.18033688011112043f   // 0.125 * log2(e), folded into Q at GEMM epilogue

typedef __attribute__((ext_vector_type(8))) short bf16x8;
typedef __attribute__((ext_vector_type(4))) short bf16x4;
typedef __attribute__((ext_vector_type(4))) float f32x4;
typedef __attribute__((ext_vector_type(4))) unsigned u32x4;

__device__ __forceinline__ float bf2f(short s){
  unsigned u = ((unsigned)(unsigned short)s) << 16;
  union { unsigned u; float f; } c; c.u = u; return c.f;
}
__device__ __forceinline__ short f2bf(float f){
  union { float f; unsigned u; } c; c.f = f;
  unsigned u = c.u;
  unsigned r = (u + 0x7FFFu + ((u >> 16) & 1u)) >> 16;
  return (short)(unsigned short)r;
}
__device__ __forceinline__ float asf(unsigned u){
  union { unsigned u; float f; } c; c.u = u; return c.f;
}

// ---------------- LayerNorm: one block per row, f32 in -> bf16 out ----------------
__global__ __launch_bounds__(256) void ln_kernel(const float* __restrict__ x,
                                                 const float* __restrict__ g,
                                                 const float* __restrict__ bb,
                                                 short* __restrict__ y)
{
  int row = blockIdx.x;
  const float* xr = x + (size_t)row * D_;
  float s = 0.f, s2 = 0.f;
  for (int i = threadIdx.x; i < D_; i += 256){
    float v = xr[i]; s += v; s2 = fmaf(v, v, s2);
  }
  #pragma unroll
  for (int off = 32; off > 0; off >>= 1){
    s  += __shfl_down(s,  off, 64);
    s2 += __shfl_down(s2, off, 64);
  }
  __shared__ float rs_[4], rs2_[4];
  int wv = threadIdx.x >> 6;
  if ((threadIdx.x & 63) == 0){ rs_[wv] = s; rs2_[wv] = s2; }
  __syncthreads();
  float ts  = rs_[0] + rs_[1] + rs_[2] + rs_[3];
  float ts2 = rs2_[0] + rs2_[1] + rs2_[2] + rs2_[3];
  float mu  = ts * (1.f / D_);
  float var = ts2 * (1.f / D_) - mu * mu;
  float rstd = rsqrtf(var + 1e-5f);
  short* yr = y + (size_t)row * D_;
  for (int i = threadIdx.x; i < D_; i += 256){
    yr[i] = f2bf((xr[i] - mu) * rstd * g[i] + bb[i]);
  }
}

// ---------------- Transpose weights: f32 W[k][n] -> bf16 Wt[n][k] ----------------
__global__ __launch_bounds__(256) void transpose_kernel(
    const float* __restrict__ Wq, const float* __restrict__ Wk,
    const float* __restrict__ Wv, const float* __restrict__ Wo,
    short* __restrict__ WqkvT, short* __restrict__ WoT)
{
  __shared__ short t[64][72];
  int z = blockIdx.z;
  const float* W = (z == 0) ? Wq : (z == 1) ? Wk : (z == 2) ? Wv : Wo;
  int kb = blockIdx.x * 64, nb = blockIdx.y * 64;
  int c0 = (threadIdx.x & 7) * 8;
  int r0 = threadIdx.x >> 3;            // 0..31
  #pragma unroll
  for (int rr = 0; rr < 64; rr += 32){
    const float* src = &W[(size_t)(kb + r0 + rr) * D_ + nb + c0];
    float4 a = *(const float4*)src;
    float4 b = *(const float4*)(src + 4);
    short* dstl = &t[r0 + rr][c0];
    dstl[0] = f2bf(a.x); dstl[1] = f2bf(a.y); dstl[2] = f2bf(a.z); dstl[3] = f2bf(a.w);
    dstl[4] = f2bf(b.x); dstl[5] = f2bf(b.y); dstl[6] = f2bf(b.z); dstl[7] = f2bf(b.w);
  }
  __syncthreads();
  short* dst = (z < 3) ? (WqkvT + (size_t)(z * D_) * D_) : WoT;
  #pragma unroll
  for (int rr = 0; rr < 64; rr += 32){
    int n = nb + r0 + rr;
    bf16x8 v;
    #pragma unroll
    for (int j = 0; j < 8; j++) v[j] = t[c0 + j][r0 + rr];
    *(bf16x8*)&dst[(size_t)n * D_ + kb + c0] = v;
  }
}

// ---------------- Prep: csb[k][q] = packed bf16(cosB, sinB); adjT[k][q] = bf16 adj^T ----
__global__ __launch_bounds__(256) void prep_kernel(
    const float* __restrict__ adj, const float* __restrict__ brg,
    unsigned* __restrict__ csb, short* __restrict__ adjT)
{
  int kt = blockIdx.x, qt = blockIdx.y;
  int r  = threadIdx.x >> 2;          // 0..63
  int c0 = (threadIdx.x & 3) * 16;    // 0..48
  {
    int k = kt * 64 + r;
    const float* bp = brg + (size_t)k * N_ + qt * 64 + c0;
    unsigned* cp = csb + (size_t)k * N_ + qt * 64 + c0;
    #pragma unroll
    for (int i = 0; i < 16; i += 4){
      float4 bv = *(const float4*)(bp + i);
      float b4[4] = { bv.x, bv.y, bv.z, bv.w };
      unsigned o[4];
      #pragma unroll
      for (int j = 0; j < 4; j++){
        float Br = (b4[j] + 180.f) * 0.017453292519943295f;
        float sB, cB;
        __sincosf(Br, &sB, &cB);
        o[j] = ((unsigned)(unsigned short)f2bf(cB)) |
               (((unsigned)(unsigned short)f2bf(sB)) << 16);
      }
      *(uint4*)(cp + i) = make_uint4(o[0], o[1], o[2], o[3]);
    }
  }
  __shared__ short tt[64][72];
  {
    int q = qt * 64 + r;
    const float* ap = adj + (size_t)q * N_ + kt * 64 + c0;
    #pragma unroll
    for (int i = 0; i < 16; i += 4){
      float4 av = *(const float4*)(ap + i);
      tt[r][c0 + i]     = f2bf(av.x);
      tt[r][c0 + i + 1] = f2bf(av.y);
      tt[r][c0 + i + 2] = f2bf(av.z);
      tt[r][c0 + i + 3] = f2bf(av.w);
    }
  }
  __syncthreads();
  {
    int k = kt * 64 + r;
    short* op = adjT + (size_t)k * N_ + qt * 64 + c0;
    bf16x8 v0, v1;
    #pragma unroll
    for (int j = 0; j < 8; j++){ v0[j] = tt[c0 + j][r]; v1[j] = tt[c0 + 8 + j][r]; }
    *(bf16x8*)op = v0;
    *(bf16x8*)(op + 8) = v1;
  }
}

// ---------------- align table: alignT[b][k][q] = bf16 cos(wd[b,q] - (brg[k,q]+180)) ----
// h-independent part of the wind bias, hoisted out of the 14-head attn loop.
__global__ __launch_bounds__(256) void align_kernel(const float* __restrict__ brg,
                                                    const float* __restrict__ wdir,
                                                    short* __restrict__ alignT)
{
  int kt = blockIdx.x;     // 0..15
  int b  = blockIdx.y;     // 0..7
  __shared__ float cA[N_], sA[N_];
  for (int q = threadIdx.x; q < N_; q += 256){
    float A = wdir[(size_t)b * N_ + q] * 0.017453292519943295f;
    float s, c; __sincosf(A, &s, &c);
    sA[q] = s; cA[q] = c;
  }
  __syncthreads();
  int q4 = threadIdx.x * 4;           // 0..1020
  for (int kr = 0; kr < 64; kr++){
    int k = kt * 64 + kr;
    float4 bv = *(const float4*)(brg + (size_t)k * N_ + q4);
    float b4[4] = { bv.x, bv.y, bv.z, bv.w };
    unsigned oo[2];
    #pragma unroll
    for (int p = 0; p < 2; p++){
      unsigned lo = 0, hi = 0;
      #pragma unroll
      for (int j = 0; j < 2; j++){
        int qq = q4 + p * 2 + j;
        float Br = (b4[p * 2 + j] + 180.f) * 0.017453292519943295f;
        float sB, cB; __sincosf(Br, &sB, &cB);
        float al = fmaf(cA[qq], cB, sA[qq] * sB);
        unsigned v = (unsigned)(unsigned short)f2bf(al);
        if (j == 0) lo = v; else hi = v;
      }
      oo[p] = lo | (hi << 16);
    }
    *(uint2*)(alignT + ((size_t)b * N_ + k) * N_ + q4) = make_uint2(oo[0], oo[1]);
  }
}

// ---------------- MFMA GEMM: C[M x N] = A[M x K] * Bt[N x K]^T ----------------
// rope!=0 (QKV gemm): apply RoPE + Q-scale (0.125*log2e) in-register before the
// bf16 store. Head span (64 cols) == one wave's j-span, so pairs (i, i+32) are
// acc[i][j] / acc[i][j+2] of the same thread.
__global__ __launch_bounds__(256) void gemm_bt(const short* __restrict__ A,
                                               const short* __restrict__ Bt,
                                               short* __restrict__ C,
                                               float* __restrict__ Cf,
                                               const float* __restrict__ residf,
                                               int N, int rope)
{
  const int K = D_;
  __shared__ short As[128 * 32];
  __shared__ short Bs[128 * 32];
  int tid  = threadIdx.x;
  int wave = tid >> 6;
  int lane = tid & 63;
  int quad = lane >> 4;
  int l16  = lane & 15;
  int wr = wave >> 1, wc = wave & 1;
  int m0 = blockIdx.x * 128;
  int n0 = blockIdx.y * 128;

  f32x4 acc[4][4];
  #pragma unroll
  for (int i = 0; i < 4; i++)
    #pragma unroll
    for (int j = 0; j < 4; j++)
      acc[i][j] = (f32x4){0.f, 0.f, 0.f, 0.f};

  for (int k0 = 0; k0 < K; k0 += 32){
    __syncthreads();
    #pragma unroll
    for (int it = 0; it < 2; ++it){
      int c   = tid + it * 256;
      int row = c >> 2;
      int cc  = c & 3;
      const short* ga = A  + (size_t)(m0 + row) * K + k0 + cc * 8;
      const short* gb = Bt + (size_t)(n0 + row) * K + k0 + cc * 8;
      short* la = As + (size_t)(wave * 64 + it * 256) * 8;
      short* lb = Bs + (size_t)(wave * 64 + it * 256) * 8;
      __builtin_amdgcn_global_load_lds((const __attribute__((address_space(1))) void*)ga,
                                       (__attribute__((address_space(3))) void*)la, 16, 0, 0);
      __builtin_amdgcn_global_load_lds((const __attribute__((address_space(1))) void*)gb,
                                       (__attribute__((address_space(3))) void*)lb, 16, 0, 0);
    }
    __syncthreads();

    bf16x8 af[4], bfr[4];
    #pragma unroll
    for (int i = 0; i < 4; i++)
      af[i] = *(const bf16x8*)(As + (size_t)(wr * 64 + i * 16 + l16) * 32 + quad * 8);
    #pragma unroll
    for (int j = 0; j < 4; j++)
      bfr[j] = *(const bf16x8*)(Bs + (size_t)(wc * 64 + j * 16 + l16) * 32 + quad * 8);
    #pragma unroll
    for (int i = 0; i < 4; i++)
      #pragma unroll
      for (int j = 0; j < 4; j++)
        acc[i][j] = __builtin_amdgcn_mfma_f32_16x16x32_bf16(af[i], bfr[j], acc[i][j], 0, 0, 0);
  }

  if (rope){
    int cb  = n0 + wc * 64;            // head base col (64-aligned)
    int mat = cb / D_;                 // 0=Q, 1=K, 2=V
    if (mat < 2){
      float scale = (mat == 0) ? QSCALE_ : 1.0f;
      float invf0 = exp2f(-0.4152410118609203f * (float)l16);  // 10000^(-l16/32)
      float invf1 = invf0 * 0.01f;                             // 10000^(-(16+l16)/32)
      #pragma unroll
      for (int i = 0; i < 4; i++){
        #pragma unroll
        for (int rr = 0; rr < 4; rr++){
          int r = m0 + wr * 64 + i * 16 + quad * 4 + rr;
          float nseq = (float)(r & (N_ - 1));
          float s0, c0v, s1, c1v;
          __sincosf(nseq * invf0, &s0, &c0v);
          __sincosf(nseq * invf1, &s1, &c1v);
          float x1 = acc[i][0][rr], x2 = acc[i][2][rr];
          acc[i][0][rr] = (x1 * c0v - x2 * s0) * scale;
          acc[i][2][rr] = (x2 * c0v + x1 * s0) * scale;
          x1 = acc[i][1][rr]; x2 = acc[i][3][rr];
          acc[i][1][rr] = (x1 * c1v - x2 * s1) * scale;
          acc[i][3][rr] = (x2 * c1v + x1 * s1) * scale;
        }
      }
    }
  }

  #pragma unroll
  for (int i = 0; i < 4; i++){
    #pragma unroll
    for (int rr = 0; rr < 4; rr++){
      int r = m0 + wr * 64 + i * 16 + quad * 4 + rr;
      size_t rowoff = (size_t)r * N;
      #pragma unroll
      for (int j = 0; j < 4; j++){
        int cidx = n0 + wc * 64 + j * 16 + l16;
        float v = acc[i][j][rr];
        if (Cf){
          Cf[rowoff + cidx] = v + residf[rowoff + cidx];
        } else {
          C[rowoff + cidx] = f2bf(v);
        }
      }
    }
  }
}

// ---------------- MFMA flash attention, fixed-max softmax, exp2 domain ----------------
// Q pre-scaled by 0.125*log2e in GEMM epilogue -> S' = log2e * QK/8.
// weights = exp2(S'(masked) + log2e*(tanh(z) - M0)); normalization cancels the base.
// PRE=1: align precomputed per (b,k,q) (shared across 14 heads); PRE=0: inline from csb.
// K/V global loads for tile kt+1 issued right after the staging barrier of tile kt:
// they fly under QK+bias+PV, so the vmcnt-drain at the next __syncthreads is free.
// __launch_bounds__(512,4): 128-VGPR budget. Do not tighten (loop spill at (512,6)).
__global__ __launch_bounds__(512, 4)
__global__ void attn_dummy(); // fwd decl spacing guard (unused)

template<int PRE>
__global__ __launch_bounds__(512, 4) void attn_kernel(
    const short* __restrict__ QKV,
    const unsigned* __restrict__ csb,   // [k][q] packed (cosB lo16, sinB hi16)  (PRE=0)
    const short* __restrict__ adjT,     // [k][q] bf16
    const short* __restrict__ alignT,   // [b][k][q] bf16                         (PRE=1)
    const float* __restrict__ wind_dirs,
    const float* __restrict__ wind_w,
    const float* __restrict__ wind_b,
    short* __restrict__ outb)
{
  __shared__ short K_s[64 * 72];       // K[k][d]
  __shared__ short V_t[64 * 76];       // V^T[d][k]
  __shared__ short P_s[128 * 76];      // P[q][k]

  int bid = blockIdx.x;
  int qt  = bid & 7;
  int hh  = (bid >> 3) % H_;
  int b   = bid / (8 * H_);
  int q0  = qt * 128;

  int t    = threadIdx.x;
  int w    = t >> 6;          // 0..7
  int lane = t & 63;
  int quad = lane >> 4;
  int l16  = lane & 15;

  // Q fragments (A-operand): m = l16 (q row in wave), k = kc*32 + quad*8 + j
  const short* qp = QKV + ((size_t)(b * N_) + q0 + w * 16 + l16) * DQKV_ + hh * DH_;
  bf16x8 qf0 = *(const bf16x8*)(qp + quad * 8);
  bf16x8 qf1 = *(const bf16x8*)(qp + 32 + quad * 8);

  // wind dir trig per q-row -- only needed when align is computed inline
  float cA[4], sA[4];
  if (!PRE){
    #pragma unroll
    for (int rr = 0; rr < 4; rr++){
      float wd = wind_dirs[(size_t)b * N_ + q0 + w * 16 + quad * 4 + rr];
      float A  = wd * 0.017453292519943295f;
      sA[rr] = __sinf(A);
      cA[rr] = __cosf(A);
    }
  }
  // weights pre-scaled by 2*log2e so e^{2z} = exp2(z2) with no extra multiply
  float w0m = wind_w[hh]      * TWO_LOG2E_;
  float w1m = wind_w[H_ + hh] * TWO_LOG2E_;
  float wbm = wind_b[hh]      * TWO_LOG2E_;

  float l[4] = {0.f, 0.f, 0.f, 0.f};
  f32x4 O[4];
  #pragma unroll
  for (int dc = 0; dc < 4; dc++) O[dc] = (f32x4){0.f, 0.f, 0.f, 0.f};

  // staging indices
  int kr  = t >> 3, kc8 = (t & 7) * 8;          // K rows (1 bf16x8 per thread)
  int vk2 = (t >> 4) * 2, vd4 = (t & 15) * 4;   // V: 2 k-rows x 4 d per thread
  const short* kg0 = QKV + ((size_t)(b * N_) + kr)  * DQKV_ + D_     + hh * DH_ + kc8;
  const short* vg0 = QKV + ((size_t)(b * N_) + vk2) * DQKV_ + 2 * D_ + hh * DH_ + vd4;

  // prologue prefetch (tile 0)
  bf16x8 pk  = *(const bf16x8*)kg0;
  bf16x4 pv0 = *(const bf16x4*)vg0;
  bf16x4 pv1 = *(const bf16x4*)(vg0 + DQKV_);

  for (int kt = 0; kt < 16; ++kt){
    int k0 = kt * 64;
    __syncthreads();                       // prev tile's LDS reads done; prefetch landed
    *(bf16x8*)(K_s + kr * 72 + kc8) = pk;
    #pragma unroll
    for (int j = 0; j < 4; j++){
      unsigned pv = ((unsigned)(unsigned short)pv0[j]) |
                    (((unsigned)(unsigned short)pv1[j]) << 16);
      *(unsigned*)(V_t + (vd4 + j) * 76 + vk2) = pv;
    }
    __syncthreads();                       // staging visible (lgkm drained)

    // issue next tile's K/V prefetch -- in flight under the whole compute phase
    {
      int kn = (kt < 15) ? (k0 + 64) : k0;
      pk  = *(const bf16x8*)(kg0 + (size_t)kn * DQKV_);
      pv0 = *(const bf16x4*)(vg0 + (size_t)kn * DQKV_);
      pv1 = *(const bf16x4*)(vg0 + (size_t)(kn + 1) * DQKV_);
    }

    // issue bias-input global loads early (hide under QK MFMA)
    u32x4 cs4a[4]; bf16x4 al4a[4]; bf16x4 av4a[4];
    #pragma unroll
    for (int jc = 0; jc < 4; jc++){
      size_t off = (size_t)(k0 + jc * 16 + l16) * N_ + q0 + w * 16 + quad * 4;
      if (PRE) al4a[jc] = *(const bf16x4*)(alignT + (size_t)b * N_ * N_ + off);
      else     cs4a[jc] = *(const u32x4*)(csb + off);
      av4a[jc] = *(const bf16x4*)(adjT + off);
    }

    // S = Q K^T  (rows q, cols k) -- already in exp2 domain via Q scale
    f32x4 S[4];
    __builtin_amdgcn_s_setprio(1);
    #pragma unroll
    for (int jc = 0; jc < 4; jc++){
      S[jc] = (f32x4){0.f, 0.f, 0.f, 0.f};
      bf16x8 kf0 = *(const bf16x8*)(K_s + (jc * 16 + l16) * 72 + quad * 8);
      bf16x8 kf1 = *(const bf16x8*)(K_s + (jc * 16 + l16) * 72 + 32 + quad * 8);
      S[jc] = __builtin_amdgcn_mfma_f32_16x16x32_bf16(qf0, kf0, S[jc], 0, 0, 0);
      S[jc] = __builtin_amdgcn_mfma_f32_16x16x32_bf16(qf1, kf1, S[jc], 0, 0, 0);
    }
    __builtin_amdgcn_s_setprio(0);

    // bias + mask + exp2(S' + log2e*(bias - M0)), accumulate l, write P
    #pragma unroll
    for (int jc = 0; jc < 4; jc++){
      #pragma unroll
      for (int rr = 0; rr < 4; rr++){
        float av = bf2f(av4a[jc][rr]);
        float align;
        if (PRE){
          align = bf2f(al4a[jc][rr]);
        } else {
          unsigned u = cs4a[jc][rr];
          float cB = asf(u << 16);
          float sB = asf(u & 0xffff0000u);
          align = cA[rr] * cB + sA[rr] * sB;
        }
        float z2 = fmaf(align, w0m, fmaf(av, w1m, wbm));    // 2*log2e*z
        float e2 = __builtin_amdgcn_exp2f(z2);              // e^{2z}
        float rc = __builtin_amdgcn_rcpf(e2 + 1.f);
        float bias2 = fmaf(-TWO_LOG2E_, rc, BIAS_C_);       // log2e*(tanh(z) - M0)
        float sv = (av > 0.f ? S[jc][rr] : -1e30f) + bias2;
        float e = __builtin_amdgcn_exp2f(sv);
        l[rr] += e;
        P_s[(w * 16 + quad * 4 + rr) * 76 + jc * 16 + l16] = f2bf(e);
      }
    }

    // PV (A-layout read of own P rows; V_t from barrier-protected stage)
    __builtin_amdgcn_s_setprio(1);
    #pragma unroll
    for (int kc = 0; kc < 2; kc++){
      const short* pp = P_s + (w * 16 + l16) * 76 + kc * 32 + quad * 8;
      bf16x4 p0 = *(const bf16x4*)pp;
      bf16x4 p1 = *(const bf16x4*)(pp + 4);
      bf16x8 pf = { p0[0], p0[1], p0[2], p0[3], p1[0], p1[1], p1[2], p1[3] };
      #pragma unroll
      for (int dc = 0; dc < 4; dc++){
        const short* vp = V_t + (dc * 16 + l16) * 76 + kc * 32 + quad * 8;
        bf16x4 u0 = *(const bf16x4*)vp;
        bf16x4 u1 = *(const bf16x4*)(vp + 4);
        bf16x8 vf = { u0[0], u0[1], u0[2], u0[3], u1[0], u1[1], u1[2], u1[3] };
        O[dc] = __builtin_amdgcn_mfma_f32_16x16x32_bf16(pf, vf, O[dc], 0, 0, 0);
      }
    }
    __builtin_amdgcn_s_setprio(0);
  }

  // epilogue: reduce l across the 16 lanes of the row group, O / l, write bf16
  float rl[4];
  #pragma unroll
  for (int rr = 0; rr < 4; rr++){
    float rs = l[rr];
    rs += __shfl_xor(rs, 1);
    rs += __shfl_xor(rs, 2);
    rs += __shfl_xor(rs, 4);
    rs += __shfl_xor(rs, 8);
    rl[rr] = 1.f / rs;
  }
  short* op = outb + ((size_t)(b * N_) + q0 + w * 16) * D_ + hh * DH_;
  #pragma unroll
  for (int rr = 0; rr < 4; rr++)
    #pragma unroll
    for (int dc = 0; dc < 4; dc++)
      op[(size_t)(quad * 4 + rr) * D_ + dc * 16 + l16] = f2bf(O[dc][rr] * rl[rr]);
}

extern "C" void kernel_launch(void* const* d_in, const int* in_sizes, int n_in,
                              void* d_out, int out_size, void* d_ws, size_t ws_size,
                              hipStream_t stream)
{
  const float* nf   = (const float*)d_in[0];
  const float* adj  = (const float*)d_in[1];
  const float* wdir = (const float*)d_in[2];
  const float* brg  = (const float*)d_in[3];
  const float* Wq   = (const float*)d_in[4];
  const float* Wk   = (const float*)d_in[5];
  const float* Wv   = (const float*)d_in[6];
  const float* Wo   = (const float*)d_in[7];
  const float* lng  = (const float*)d_in[8];
  const float* lnb  = (const float*)d_in[9];
  const float* ww   = (const float*)d_in[10];
  const float* wbb  = (const float*)d_in[11];
  float* out = (float*)d_out;

  short* base = (short*)d_ws;
  size_t sh = 0;
  short* xln   = base + sh;  sh += (size_t)M_ * D_;        // reused as attn out
  short* WqkvT = base + sh;  sh += (size_t)DQKV_ * D_;
  short* WoT   = base + sh;  sh += (size_t)D_ * D_;
  short* QKV   = base + sh;  sh += (size_t)M_ * DQKV_;
  unsigned* csb = (unsigned*)(base + sh); sh += (size_t)N_ * N_ * 2;  // u32 = 2 shorts
  short* adjT  = base + sh;  sh += (size_t)N_ * N_;
  short* alignT = base + sh; sh += (size_t)B_ * N_ * N_;
  size_t need_pre = sh * sizeof(short);
  bool pre = (ws_size >= need_pre);

  ln_kernel<<<M_, 256, 0, stream>>>(nf, lng, lnb, xln);
  transpose_kernel<<<dim3(14, 14, 4), 256, 0, stream>>>(Wq, Wk, Wv, Wo, WqkvT, WoT);
  prep_kernel<<<dim3(16, 16), 256, 0, stream>>>(adj, brg, csb, adjT);
  if (pre)
    align_kernel<<<dim3(16, 8), 256, 0, stream>>>(brg, wdir, alignT);
  gemm_bt<<<dim3(M_ / 128, DQKV_ / 128), 256, 0, stream>>>(xln, WqkvT, QKV, nullptr, nullptr, DQKV_, 1);
  if (pre)
    attn_kernel<1><<<B_ * H_ * 8, 512, 0, stream>>>(QKV, csb, adjT, alignT, wdir, ww, wbb, xln);
  else
    attn_kernel<0><<<B_ * H_ * 8, 512, 0, stream>>>(QKV, csb, adjT, alignT, wdir, ww, wbb, xln);
  gemm_bt<<<dim3(M_ / 128, D_ / 128), 256, 0, stream>>>(xln, WoT, nullptr, out, nf, D_, 0);
}

// Round 2
// 388.941 us; speedup vs baseline: 1.0431x; 1.0431x over previous
//
#include <hip/hip_runtime.h>
#include <hip/hip_bf16.h>
#include <math.h>

#define B_ 8
#define N_ 1024
#define H_ 14
#define DH_ 64
#define D_ 896
#define M_ (B_*N_)        // 8192 rows
#define DQKV_ 2688        // 3*D_

// exp2-domain constants: 2*log2(e), log2(e)*(1 - M0) with M0 = 12
#define TWO_LOG2E_ 2.8853900817779268f
#define BIAS_C_   (-15.869645449778597f)
#define QSCALE_     0.18033688011112043f   // 0.125 * log2(e), folded into Q at GEMM epilogue

typedef __attribute__((ext_vector_type(8))) short bf16x8;
typedef __attribute__((ext_vector_type(4))) short bf16x4;
typedef __attribute__((ext_vector_type(4))) float f32x4;
typedef __attribute__((ext_vector_type(4))) unsigned u32x4;

__device__ __forceinline__ float bf2f(short s){
  unsigned u = ((unsigned)(unsigned short)s) << 16;
  union { unsigned u; float f; } c; c.u = u; return c.f;
}
__device__ __forceinline__ short f2bf(float f){
  union { float f; unsigned u; } c; c.f = f;
  unsigned u = c.u;
  unsigned r = (u + 0x7FFFu + ((u >> 16) & 1u)) >> 16;
  return (short)(unsigned short)r;
}
__device__ __forceinline__ float asf(unsigned u){
  union { unsigned u; float f; } c; c.u = u; return c.f;
}

// raw workgroup barrier: LDS visibility only (lgkm), does NOT drain vmcnt ->
// global register-prefetches stay in flight across it (T14/T4-lite).
#define BAR_LDS() do { asm volatile("s_waitcnt lgkmcnt(0)" ::: "memory"); \
                       __builtin_amdgcn_s_barrier(); } while (0)

// ---------------- LayerNorm: one block per row, f32 in -> bf16 out ----------------
__global__ __launch_bounds__(256) void ln_kernel(const float* __restrict__ x,
                                                 const float* __restrict__ g,
                                                 const float* __restrict__ bb,
                                                 short* __restrict__ y)
{
  int row = blockIdx.x;
  const float* xr = x + (size_t)row * D_;
  float s = 0.f, s2 = 0.f;
  for (int i = threadIdx.x; i < D_; i += 256){
    float v = xr[i]; s += v; s2 = fmaf(v, v, s2);
  }
  #pragma unroll
  for (int off = 32; off > 0; off >>= 1){
    s  += __shfl_down(s,  off, 64);
    s2 += __shfl_down(s2, off, 64);
  }
  __shared__ float rs_[4], rs2_[4];
  int wv = threadIdx.x >> 6;
  if ((threadIdx.x & 63) == 0){ rs_[wv] = s; rs2_[wv] = s2; }
  __syncthreads();
  float ts  = rs_[0] + rs_[1] + rs_[2] + rs_[3];
  float ts2 = rs2_[0] + rs2_[1] + rs2_[2] + rs2_[3];
  float mu  = ts * (1.f / D_);
  float var = ts2 * (1.f / D_) - mu * mu;
  float rstd = rsqrtf(var + 1e-5f);
  short* yr = y + (size_t)row * D_;
  for (int i = threadIdx.x; i < D_; i += 256){
    yr[i] = f2bf((xr[i] - mu) * rstd * g[i] + bb[i]);
  }
}

// ---------------- Transpose weights: f32 W[k][n] -> bf16 Wt[n][k] ----------------
__global__ __launch_bounds__(256) void transpose_kernel(
    const float* __restrict__ Wq, const float* __restrict__ Wk,
    const float* __restrict__ Wv, const float* __restrict__ Wo,
    short* __restrict__ WqkvT, short* __restrict__ WoT)
{
  __shared__ short t[64][72];
  int z = blockIdx.z;
  const float* W = (z == 0) ? Wq : (z == 1) ? Wk : (z == 2) ? Wv : Wo;
  int kb = blockIdx.x * 64, nb = blockIdx.y * 64;
  int c0 = (threadIdx.x & 7) * 8;
  int r0 = threadIdx.x >> 3;            // 0..31
  #pragma unroll
  for (int rr = 0; rr < 64; rr += 32){
    const float* src = &W[(size_t)(kb + r0 + rr) * D_ + nb + c0];
    float4 a = *(const float4*)src;
    float4 b = *(const float4*)(src + 4);
    short* dstl = &t[r0 + rr][c0];
    dstl[0] = f2bf(a.x); dstl[1] = f2bf(a.y); dstl[2] = f2bf(a.z); dstl[3] = f2bf(a.w);
    dstl[4] = f2bf(b.x); dstl[5] = f2bf(b.y); dstl[6] = f2bf(b.z); dstl[7] = f2bf(b.w);
  }
  __syncthreads();
  short* dst = (z < 3) ? (WqkvT + (size_t)(z * D_) * D_) : WoT;
  #pragma unroll
  for (int rr = 0; rr < 64; rr += 32){
    int n = nb + r0 + rr;
    bf16x8 v;
    #pragma unroll
    for (int j = 0; j < 8; j++) v[j] = t[c0 + j][r0 + rr];
    *(bf16x8*)&dst[(size_t)n * D_ + kb + c0] = v;
  }
}

// ---------------- Prep: csb[k][q], adjT[k][q], and (do_align) alignT[b][k][q] ----
// alignT = cos(wind_dir[b,q] - (brg[k,q]+180)) -- reuses the cB/sB sincos already
// computed for csb, so the standalone align pass (and its 8x brg re-read) is gone.
__global__ __launch_bounds__(256) void prep_kernel(
    const float* __restrict__ adj, const float* __restrict__ brg,
    const float* __restrict__ wdir,
    unsigned* __restrict__ csb, short* __restrict__ adjT,
    short* __restrict__ alignT, int do_align)
{
  int kt = blockIdx.x, qt = blockIdx.y;
  __shared__ short tt[64][72];
  __shared__ float cA_[8][64], sA_[8][64];

  if (do_align){
    for (int idx = threadIdx.x; idx < 8 * 64; idx += 256){
      int b = idx >> 6, q = idx & 63;
      float A = wdir[(size_t)b * N_ + qt * 64 + q] * 0.017453292519943295f;
      float s, c; __sincosf(A, &s, &c);
      sA_[b][q] = s; cA_[b][q] = c;
    }
  }

  int r  = threadIdx.x >> 2;          // 0..63
  int c0 = (threadIdx.x & 3) * 16;    // 0..48

  // adj -> tt staging (for adjT transpose)
  {
    int q = qt * 64 + r;
    const float* ap = adj + (size_t)q * N_ + kt * 64 + c0;
    #pragma unroll
    for (int i = 0; i < 16; i += 4){
      float4 av = *(const float4*)(ap + i);
      tt[r][c0 + i]     = f2bf(av.x);
      tt[r][c0 + i + 1] = f2bf(av.y);
      tt[r][c0 + i + 2] = f2bf(av.z);
      tt[r][c0 + i + 3] = f2bf(av.w);
    }
  }
  __syncthreads();   // covers both cA_/sA_ and tt

  // csb + alignT from brg (both [k][q], coalesced)
  {
    int k = kt * 64 + r;
    const float* bp = brg + (size_t)k * N_ + qt * 64 + c0;
    unsigned* cp = csb + (size_t)k * N_ + qt * 64 + c0;
    #pragma unroll
    for (int i = 0; i < 16; i += 4){
      float4 bv = *(const float4*)(bp + i);
      float b4[4] = { bv.x, bv.y, bv.z, bv.w };
      float cB[4], sB[4];
      unsigned o[4];
      #pragma unroll
      for (int j = 0; j < 4; j++){
        float Br = (b4[j] + 180.f) * 0.017453292519943295f;
        __sincosf(Br, &sB[j], &cB[j]);
        o[j] = ((unsigned)(unsigned short)f2bf(cB[j])) |
               (((unsigned)(unsigned short)f2bf(sB[j])) << 16);
      }
      *(uint4*)(cp + i) = make_uint4(o[0], o[1], o[2], o[3]);
      if (do_align){
        #pragma unroll
        for (int b = 0; b < 8; b++){
          unsigned w2[2];
          #pragma unroll
          for (int p = 0; p < 2; p++){
            unsigned lo = 0, hi = 0;
            #pragma unroll
            for (int j = 0; j < 2; j++){
              int q = c0 + i + p * 2 + j;
              float al = fmaf(cA_[b][q], cB[p * 2 + j], sA_[b][q] * sB[p * 2 + j]);
              unsigned v = (unsigned)(unsigned short)f2bf(al);
              if (j == 0) lo = v; else hi = v;
            }
            w2[p] = lo | (hi << 16);
          }
          *(uint2*)(alignT + ((size_t)b * N_ + k) * N_ + qt * 64 + c0 + i) =
              make_uint2(w2[0], w2[1]);
        }
      }
    }
  }

  // adjT via LDS transpose
  {
    int k = kt * 64 + r;
    short* op = adjT + (size_t)k * N_ + qt * 64 + c0;
    bf16x8 v0, v1;
    #pragma unroll
    for (int j = 0; j < 8; j++){ v0[j] = tt[c0 + j][r]; v1[j] = tt[c0 + 8 + j][r]; }
    *(bf16x8*)op = v0;
    *(bf16x8*)(op + 8) = v1;
  }
}

// ---------------- MFMA GEMM: C[M x N] = A[M x K] * Bt[N x K]^T ----------------
// rope!=0 (QKV gemm): apply RoPE + Q-scale (0.125*log2e) in-register before the
// bf16 store. Head span (64 cols) == one wave's j-span, so pairs (i, i+32) are
// acc[i][j] / acc[i][j+2] of the same thread.
__global__ __launch_bounds__(256) void gemm_bt(const short* __restrict__ A,
                                               const short* __restrict__ Bt,
                                               short* __restrict__ C,
                                               float* __restrict__ Cf,
                                               const float* __restrict__ residf,
                                               int N, int rope)
{
  const int K = D_;
  __shared__ short As[128 * 32];
  __shared__ short Bs[128 * 32];
  int tid  = threadIdx.x;
  int wave = tid >> 6;
  int lane = tid & 63;
  int quad = lane >> 4;
  int l16  = lane & 15;
  int wr = wave >> 1, wc = wave & 1;
  int m0 = blockIdx.x * 128;
  int n0 = blockIdx.y * 128;

  f32x4 acc[4][4];
  #pragma unroll
  for (int i = 0; i < 4; i++)
    #pragma unroll
    for (int j = 0; j < 4; j++)
      acc[i][j] = (f32x4){0.f, 0.f, 0.f, 0.f};

  for (int k0 = 0; k0 < K; k0 += 32){
    __syncthreads();
    #pragma unroll
    for (int it = 0; it < 2; ++it){
      int c   = tid + it * 256;
      int row = c >> 2;
      int cc  = c & 3;
      const short* ga = A  + (size_t)(m0 + row) * K + k0 + cc * 8;
      const short* gb = Bt + (size_t)(n0 + row) * K + k0 + cc * 8;
      short* la = As + (size_t)(wave * 64 + it * 256) * 8;
      short* lb = Bs + (size_t)(wave * 64 + it * 256) * 8;
      __builtin_amdgcn_global_load_lds((const __attribute__((address_space(1))) void*)ga,
                                       (__attribute__((address_space(3))) void*)la, 16, 0, 0);
      __builtin_amdgcn_global_load_lds((const __attribute__((address_space(1))) void*)gb,
                                       (__attribute__((address_space(3))) void*)lb, 16, 0, 0);
    }
    __syncthreads();

    bf16x8 af[4], bfr[4];
    #pragma unroll
    for (int i = 0; i < 4; i++)
      af[i] = *(const bf16x8*)(As + (size_t)(wr * 64 + i * 16 + l16) * 32 + quad * 8);
    #pragma unroll
    for (int j = 0; j < 4; j++)
      bfr[j] = *(const bf16x8*)(Bs + (size_t)(wc * 64 + j * 16 + l16) * 32 + quad * 8);
    #pragma unroll
    for (int i = 0; i < 4; i++)
      #pragma unroll
      for (int j = 0; j < 4; j++)
        acc[i][j] = __builtin_amdgcn_mfma_f32_16x16x32_bf16(af[i], bfr[j], acc[i][j], 0, 0, 0);
  }

  if (rope){
    int cb  = n0 + wc * 64;            // head base col (64-aligned)
    int mat = cb / D_;                 // 0=Q, 1=K, 2=V
    if (mat < 2){
      float scale = (mat == 0) ? QSCALE_ : 1.0f;
      float invf0 = exp2f(-0.4152410118609203f * (float)l16);  // 10000^(-l16/32)
      float invf1 = invf0 * 0.01f;                             // 10000^(-(16+l16)/32)
      #pragma unroll
      for (int i = 0; i < 4; i++){
        #pragma unroll
        for (int rr = 0; rr < 4; rr++){
          int r = m0 + wr * 64 + i * 16 + quad * 4 + rr;
          float nseq = (float)(r & (N_ - 1));
          float s0, c0v, s1, c1v;
          __sincosf(nseq * invf0, &s0, &c0v);
          __sincosf(nseq * invf1, &s1, &c1v);
          float x1 = acc[i][0][rr], x2 = acc[i][2][rr];
          acc[i][0][rr] = (x1 * c0v - x2 * s0) * scale;
          acc[i][2][rr] = (x2 * c0v + x1 * s0) * scale;
          x1 = acc[i][1][rr]; x2 = acc[i][3][rr];
          acc[i][1][rr] = (x1 * c1v - x2 * s1) * scale;
          acc[i][3][rr] = (x2 * c1v + x1 * s1) * scale;
        }
      }
    }
  }

  #pragma unroll
  for (int i = 0; i < 4; i++){
    #pragma unroll
    for (int rr = 0; rr < 4; rr++){
      int r = m0 + wr * 64 + i * 16 + quad * 4 + rr;
      size_t rowoff = (size_t)r * N;
      #pragma unroll
      for (int j = 0; j < 4; j++){
        int cidx = n0 + wc * 64 + j * 16 + l16;
        float v = acc[i][j][rr];
        if (Cf){
          Cf[rowoff + cidx] = v + residf[rowoff + cidx];
        } else {
          C[rowoff + cidx] = f2bf(v);
        }
      }
    }
  }
}

// ---------------- MFMA flash attention, fixed-max softmax, exp2 domain ----------------
// Latency-bound kernel (r1 counters: VALU 51.6->37.9% with dur flat). Fixes:
//  * raw barriers (lgkm-only) -> vmcnt never drained at barriers, so register
//    prefetches genuinely span them;
//  * K/V prefetched 1 tile ahead (window = full compute phase);
//  * bias inputs (align/adj) prefetched 1 tile ahead -- issued right after the
//    current tile's bias math consumed them, landing during PV+staging+QK.
// __launch_bounds__(512,4): 128-VGPR budget. Do not tighten (loop spill at (512,6)).
template<int PRE>
__global__ __launch_bounds__(512, 4) void attn_kernel(
    const short* __restrict__ QKV,
    const unsigned* __restrict__ csb,   // [k][q] packed (cosB lo16, sinB hi16)  (PRE=0)
    const short* __restrict__ adjT,     // [k][q] bf16
    const short* __restrict__ alignT,   // [b][k][q] bf16                         (PRE=1)
    const float* __restrict__ wind_dirs,
    const float* __restrict__ wind_w,
    const float* __restrict__ wind_b,
    short* __restrict__ outb)
{
  __shared__ short K_s[64 * 72];       // K[k][d]
  __shared__ short V_t[64 * 76];       // V^T[d][k]
  __shared__ short P_s[128 * 76];      // P[q][k]

  int bid = blockIdx.x;
  int qt  = bid & 7;
  int hh  = (bid >> 3) % H_;
  int b   = bid / (8 * H_);
  int q0  = qt * 128;

  int t    = threadIdx.x;
  int w    = t >> 6;          // 0..7
  int lane = t & 63;
  int quad = lane >> 4;
  int l16  = lane & 15;

  // Q fragments (A-operand): m = l16 (q row in wave), k = kc*32 + quad*8 + j
  const short* qp = QKV + ((size_t)(b * N_) + q0 + w * 16 + l16) * DQKV_ + hh * DH_;
  bf16x8 qf0 = *(const bf16x8*)(qp + quad * 8);
  bf16x8 qf1 = *(const bf16x8*)(qp + 32 + quad * 8);

  // wind dir trig per q-row -- only needed when align is computed inline
  float cA[4], sA[4];
  if (!PRE){
    #pragma unroll
    for (int rr = 0; rr < 4; rr++){
      float wd = wind_dirs[(size_t)b * N_ + q0 + w * 16 + quad * 4 + rr];
      float A  = wd * 0.017453292519943295f;
      sA[rr] = __sinf(A);
      cA[rr] = __cosf(A);
    }
  }
  // weights pre-scaled by 2*log2e so e^{2z} = exp2(z2) with no extra multiply
  float w0m = wind_w[hh]      * TWO_LOG2E_;
  float w1m = wind_w[H_ + hh] * TWO_LOG2E_;
  float wbm = wind_b[hh]      * TWO_LOG2E_;

  float l[4] = {0.f, 0.f, 0.f, 0.f};
  f32x4 O[4];
  #pragma unroll
  for (int dc = 0; dc < 4; dc++) O[dc] = (f32x4){0.f, 0.f, 0.f, 0.f};

  // staging indices
  int kr  = t >> 3, kc8 = (t & 7) * 8;          // K rows (1 bf16x8 per thread)
  int vk2 = (t >> 4) * 2, vd4 = (t & 15) * 4;   // V: 2 k-rows x 4 d per thread
  const short* kg0 = QKV + ((size_t)(b * N_) + kr)  * DQKV_ + D_     + hh * DH_ + kc8;
  const short* vg0 = QKV + ((size_t)(b * N_) + vk2) * DQKV_ + 2 * D_ + hh * DH_ + vd4;

  // prologue prefetch (tile 0): K/V
  bf16x8 pk  = *(const bf16x8*)kg0;
  bf16x4 pv0 = *(const bf16x4*)vg0;
  bf16x4 pv1 = *(const bf16x4*)(vg0 + DQKV_);

  // prologue prefetch (tile 0): bias inputs
  size_t bias_q = (size_t)(q0 + w * 16 + quad * 4);
  u32x4 cs4a[4]; bf16x4 al4a[4]; bf16x4 av4a[4];
  #pragma unroll
  for (int jc = 0; jc < 4; jc++){
    size_t off = (size_t)(jc * 16 + l16) * N_ + bias_q;
    if (PRE) al4a[jc] = *(const bf16x4*)(alignT + (size_t)b * N_ * N_ + off);
    else     cs4a[jc] = *(const u32x4*)(csb + off);
    av4a[jc] = *(const bf16x4*)(adjT + off);
  }

  for (int kt = 0; kt < 16; ++kt){
    int k0 = kt * 64;
    BAR_LDS();                           // prev tile's LDS reads all consumed; WAR-safe
    *(bf16x8*)(K_s + kr * 72 + kc8) = pk;
    #pragma unroll
    for (int j = 0; j < 4; j++){
      unsigned pv = ((unsigned)(unsigned short)pv0[j]) |
                    (((unsigned)(unsigned short)pv1[j]) << 16);
      *(unsigned*)(V_t + (vd4 + j) * 76 + vk2) = pv;
    }
    BAR_LDS();                           // staging visible; vmcnt NOT drained

    // issue next tile's K/V prefetch -- in flight under the whole compute phase
    int kn = (kt < 15) ? (k0 + 64) : k0;
    pk  = *(const bf16x8*)(kg0 + (size_t)kn * DQKV_);
    pv0 = *(const bf16x4*)(vg0 + (size_t)kn * DQKV_);
    pv1 = *(const bf16x4*)(vg0 + (size_t)(kn + 1) * DQKV_);

    // S = Q K^T  (rows q, cols k) -- already in exp2 domain via Q scale
    f32x4 S[4];
    __builtin_amdgcn_s_setprio(1);
    #pragma unroll
    for (int jc = 0; jc < 4; jc++){
      S[jc] = (f32x4){0.f, 0.f, 0.f, 0.f};
      bf16x8 kf0 = *(const bf16x8*)(K_s + (jc * 16 + l16) * 72 + quad * 8);
      bf16x8 kf1 = *(const bf16x8*)(K_s + (jc * 16 + l16) * 72 + 32 + quad * 8);
      S[jc] = __builtin_amdgcn_mfma_f32_16x16x32_bf16(qf0, kf0, S[jc], 0, 0, 0);
      S[jc] = __builtin_amdgcn_mfma_f32_16x16x32_bf16(qf1, kf1, S[jc], 0, 0, 0);
    }
    __builtin_amdgcn_s_setprio(0);

    // bias + mask + exp2(S' + log2e*(bias - M0)), accumulate l, write P
    #pragma unroll
    for (int jc = 0; jc < 4; jc++){
      #pragma unroll
      for (int rr = 0; rr < 4; rr++){
        float av = bf2f(av4a[jc][rr]);
        float align;
        if (PRE){
          align = bf2f(al4a[jc][rr]);
        } else {
          unsigned u = cs4a[jc][rr];
          float cB = asf(u << 16);
          float sB = asf(u & 0xffff0000u);
          align = cA[rr] * cB + sA[rr] * sB;
        }
        float z2 = fmaf(align, w0m, fmaf(av, w1m, wbm));    // 2*log2e*z
        float e2 = __builtin_amdgcn_exp2f(z2);              // e^{2z}
        float rc = __builtin_amdgcn_rcpf(e2 + 1.f);
        float bias2 = fmaf(-TWO_LOG2E_, rc, BIAS_C_);       // log2e*(tanh(z) - M0)
        float sv = (av > 0.f ? S[jc][rr] : -1e30f) + bias2;
        float e = __builtin_amdgcn_exp2f(sv);
        l[rr] += e;
        P_s[(w * 16 + quad * 4 + rr) * 76 + jc * 16 + l16] = f2bf(e);
      }
    }

    // prefetch next tile's bias inputs (consumed next iteration after QK)
    #pragma unroll
    for (int jc = 0; jc < 4; jc++){
      size_t off = (size_t)(kn + jc * 16 + l16) * N_ + bias_q;
      if (PRE) al4a[jc] = *(const bf16x4*)(alignT + (size_t)b * N_ * N_ + off);
      else     cs4a[jc] = *(const u32x4*)(csb + off);
      av4a[jc] = *(const bf16x4*)(adjT + off);
    }

    // PV (A-layout read of own P rows; V_t from barrier-protected stage)
    __builtin_amdgcn_s_setprio(1);
    #pragma unroll
    for (int kc = 0; kc < 2; kc++){
      const short* pp = P_s + (w * 16 + l16) * 76 + kc * 32 + quad * 8;
      bf16x4 p0 = *(const bf16x4*)pp;
      bf16x4 p1 = *(const bf16x4*)(pp + 4);
      bf16x8 pf = { p0[0], p0[1], p0[2], p0[3], p1[0], p1[1], p1[2], p1[3] };
      #pragma unroll
      for (int dc = 0; dc < 4; dc++){
        const short* vp = V_t + (dc * 16 + l16) * 76 + kc * 32 + quad * 8;
        bf16x4 u0 = *(const bf16x4*)vp;
        bf16x4 u1 = *(const bf16x4*)(vp + 4);
        bf16x8 vf = { u0[0], u0[1], u0[2], u0[3], u1[0], u1[1], u1[2], u1[3] };
        O[dc] = __builtin_amdgcn_mfma_f32_16x16x32_bf16(pf, vf, O[dc], 0, 0, 0);
      }
    }
    __builtin_amdgcn_s_setprio(0);
  }

  // epilogue: reduce l across the 16 lanes of the row group, O / l, write bf16
  float rl[4];
  #pragma unroll
  for (int rr = 0; rr < 4; rr++){
    float rs = l[rr];
    rs += __shfl_xor(rs, 1);
    rs += __shfl_xor(rs, 2);
    rs += __shfl_xor(rs, 4);
    rs += __shfl_xor(rs, 8);
    rl[rr] = 1.f / rs;
  }
  short* op = outb + ((size_t)(b * N_) + q0 + w * 16) * D_ + hh * DH_;
  #pragma unroll
  for (int rr = 0; rr < 4; rr++)
    #pragma unroll
    for (int dc = 0; dc < 4; dc++)
      op[(size_t)(quad * 4 + rr) * D_ + dc * 16 + l16] = f2bf(O[dc][rr] * rl[rr]);
}

extern "C" void kernel_launch(void* const* d_in, const int* in_sizes, int n_in,
                              void* d_out, int out_size, void* d_ws, size_t ws_size,
                              hipStream_t stream)
{
  const float* nf   = (const float*)d_in[0];
  const float* adj  = (const float*)d_in[1];
  const float* wdir = (const float*)d_in[2];
  const float* brg  = (const float*)d_in[3];
  const float* Wq   = (const float*)d_in[4];
  const float* Wk   = (const float*)d_in[5];
  const float* Wv   = (const float*)d_in[6];
  const float* Wo   = (const float*)d_in[7];
  const float* lng  = (const float*)d_in[8];
  const float* lnb  = (const float*)d_in[9];
  const float* ww   = (const float*)d_in[10];
  const float* wbb  = (const float*)d_in[11];
  float* out = (float*)d_out;

  short* base = (short*)d_ws;
  size_t sh = 0;
  short* xln   = base + sh;  sh += (size_t)M_ * D_;        // reused as attn out
  short* WqkvT = base + sh;  sh += (size_t)DQKV_ * D_;
  short* WoT   = base + sh;  sh += (size_t)D_ * D_;
  short* QKV   = base + sh;  sh += (size_t)M_ * DQKV_;
  unsigned* csb = (unsigned*)(base + sh); sh += (size_t)N_ * N_ * 2;  // u32 = 2 shorts
  short* adjT  = base + sh;  sh += (size_t)N_ * N_;
  short* alignT = base + sh; sh += (size_t)B_ * N_ * N_;
  size_t need_pre = sh * sizeof(short);
  bool pre = (ws_size >= need_pre);

  ln_kernel<<<M_, 256, 0, stream>>>(nf, lng, lnb, xln);
  transpose_kernel<<<dim3(14, 14, 4), 256, 0, stream>>>(Wq, Wk, Wv, Wo, WqkvT, WoT);
  prep_kernel<<<dim3(16, 16), 256, 0, stream>>>(adj, brg, wdir, csb, adjT, alignT, pre ? 1 : 0);
  gemm_bt<<<dim3(M_ / 128, DQKV_ / 128), 256, 0, stream>>>(xln, WqkvT, QKV, nullptr, nullptr, DQKV_, 1);
  if (pre)
    attn_kernel<1><<<B_ * H_ * 8, 512, 0, stream>>>(QKV, csb, adjT, alignT, wdir, ww, wbb, xln);
  else
    attn_kernel<0><<<B_ * H_ * 8, 512, 0, stream>>>(QKV, csb, adjT, alignT, wdir, ww, wbb, xln);
  gemm_bt<<<dim3(M_ / 128, D_ / 128), 256, 0, stream>>>(xln, WoT, nullptr, out, nf, D_, 0);
}

// Round 3
// 384.384 us; speedup vs baseline: 1.0555x; 1.0119x over previous
//
#include <hip/hip_runtime.h>
#include <hip/hip_bf16.h>
#include <math.h>

#define B_ 8
#define N_ 1024
#define H_ 14
#define DH_ 64
#define D_ 896
#define M_ (B_*N_)        // 8192 rows
#define DQKV_ 2688        // 3*D_

// exp2-domain constants: 2*log2(e), log2(e)*(1 - M0) with M0 = 12
#define TWO_LOG2E_ 2.8853900817779268f
#define BIAS_C_   (-15.869645449778597f)
#define QSCALE_     0.18033688011112043f   // 0.125 * log2(e), folded into Q at GEMM epilogue

typedef __attribute__((ext_vector_type(8))) short bf16x8;
typedef __attribute__((ext_vector_type(4))) short bf16x4;
typedef __attribute__((ext_vector_type(4))) float f32x4;
typedef __attribute__((ext_vector_type(4))) unsigned u32x4;

__device__ __forceinline__ float bf2f(short s){
  unsigned u = ((unsigned)(unsigned short)s) << 16;
  union { unsigned u; float f; } c; c.u = u; return c.f;
}
__device__ __forceinline__ short f2bf(float f){
  union { float f; unsigned u; } c; c.f = f;
  unsigned u = c.u;
  unsigned r = (u + 0x7FFFu + ((u >> 16) & 1u)) >> 16;
  return (short)(unsigned short)r;
}
__device__ __forceinline__ float asf(unsigned u){
  union { unsigned u; float f; } c; c.u = u; return c.f;
}
// pack 2 f32 -> 2 bf16 in one VALU op (RNE -- bit-identical to f2bf above)
__device__ __forceinline__ unsigned cvt_pk_bf16(float lo, float hi){
  unsigned r;
  asm("v_cvt_pk_bf16_f32 %0, %1, %2" : "=v"(r) : "v"(lo), "v"(hi));
  return r;
}

// raw workgroup barrier: LDS visibility only (lgkm), does NOT drain vmcnt ->
// global register-prefetches stay in flight across it (T14/T4-lite).
#define BAR_LDS() do { asm volatile("s_waitcnt lgkmcnt(0)" ::: "memory"); \
                       __builtin_amdgcn_s_barrier(); } while (0)

// ---------------- LayerNorm: one block per row, f32 in -> bf16 out ----------------
__global__ __launch_bounds__(256) void ln_kernel(const float* __restrict__ x,
                                                 const float* __restrict__ g,
                                                 const float* __restrict__ bb,
                                                 short* __restrict__ y)
{
  int row = blockIdx.x;
  const float* xr = x + (size_t)row * D_;
  float s = 0.f, s2 = 0.f;
  for (int i = threadIdx.x; i < D_; i += 256){
    float v = xr[i]; s += v; s2 = fmaf(v, v, s2);
  }
  #pragma unroll
  for (int off = 32; off > 0; off >>= 1){
    s  += __shfl_down(s,  off, 64);
    s2 += __shfl_down(s2, off, 64);
  }
  __shared__ float rs_[4], rs2_[4];
  int wv = threadIdx.x >> 6;
  if ((threadIdx.x & 63) == 0){ rs_[wv] = s; rs2_[wv] = s2; }
  __syncthreads();
  float ts  = rs_[0] + rs_[1] + rs_[2] + rs_[3];
  float ts2 = rs2_[0] + rs2_[1] + rs2_[2] + rs2_[3];
  float mu  = ts * (1.f / D_);
  float var = ts2 * (1.f / D_) - mu * mu;
  float rstd = rsqrtf(var + 1e-5f);
  short* yr = y + (size_t)row * D_;
  for (int i = threadIdx.x; i < D_; i += 256){
    yr[i] = f2bf((xr[i] - mu) * rstd * g[i] + bb[i]);
  }
}

// ---------------- Transpose weights: f32 W[k][n] -> bf16 Wt[n][k] ----------------
__global__ __launch_bounds__(256) void transpose_kernel(
    const float* __restrict__ Wq, const float* __restrict__ Wk,
    const float* __restrict__ Wv, const float* __restrict__ Wo,
    short* __restrict__ WqkvT, short* __restrict__ WoT)
{
  __shared__ short t[64][72];
  int z = blockIdx.z;
  const float* W = (z == 0) ? Wq : (z == 1) ? Wk : (z == 2) ? Wv : Wo;
  int kb = blockIdx.x * 64, nb = blockIdx.y * 64;
  int c0 = (threadIdx.x & 7) * 8;
  int r0 = threadIdx.x >> 3;            // 0..31
  #pragma unroll
  for (int rr = 0; rr < 64; rr += 32){
    const float* src = &W[(size_t)(kb + r0 + rr) * D_ + nb + c0];
    float4 a = *(const float4*)src;
    float4 b = *(const float4*)(src + 4);
    short* dstl = &t[r0 + rr][c0];
    dstl[0] = f2bf(a.x); dstl[1] = f2bf(a.y); dstl[2] = f2bf(a.z); dstl[3] = f2bf(a.w);
    dstl[4] = f2bf(b.x); dstl[5] = f2bf(b.y); dstl[6] = f2bf(b.z); dstl[7] = f2bf(b.w);
  }
  __syncthreads();
  short* dst = (z < 3) ? (WqkvT + (size_t)(z * D_) * D_) : WoT;
  #pragma unroll
  for (int rr = 0; rr < 64; rr += 32){
    int n = nb + r0 + rr;
    bf16x8 v;
    #pragma unroll
    for (int j = 0; j < 8; j++) v[j] = t[c0 + j][r0 + rr];
    *(bf16x8*)&dst[(size_t)n * D_ + kb + c0] = v;
  }
}

// ---------------- Prep: csb[k][q], adjT[k][q], and (do_align) alignT[b][k][q] ----
__global__ __launch_bounds__(256) void prep_kernel(
    const float* __restrict__ adj, const float* __restrict__ brg,
    const float* __restrict__ wdir,
    unsigned* __restrict__ csb, short* __restrict__ adjT,
    short* __restrict__ alignT, int do_align)
{
  int kt = blockIdx.x, qt = blockIdx.y;
  __shared__ short tt[64][72];
  __shared__ float cA_[8][64], sA_[8][64];

  if (do_align){
    for (int idx = threadIdx.x; idx < 8 * 64; idx += 256){
      int b = idx >> 6, q = idx & 63;
      float A = wdir[(size_t)b * N_ + qt * 64 + q] * 0.017453292519943295f;
      float s, c; __sincosf(A, &s, &c);
      sA_[b][q] = s; cA_[b][q] = c;
    }
  }

  int r  = threadIdx.x >> 2;          // 0..63
  int c0 = (threadIdx.x & 3) * 16;    // 0..48

  // adj -> tt staging (for adjT transpose)
  {
    int q = qt * 64 + r;
    const float* ap = adj + (size_t)q * N_ + kt * 64 + c0;
    #pragma unroll
    for (int i = 0; i < 16; i += 4){
      float4 av = *(const float4*)(ap + i);
      tt[r][c0 + i]     = f2bf(av.x);
      tt[r][c0 + i + 1] = f2bf(av.y);
      tt[r][c0 + i + 2] = f2bf(av.z);
      tt[r][c0 + i + 3] = f2bf(av.w);
    }
  }
  __syncthreads();   // covers both cA_/sA_ and tt

  // csb + alignT from brg (both [k][q], coalesced)
  {
    int k = kt * 64 + r;
    const float* bp = brg + (size_t)k * N_ + qt * 64 + c0;
    unsigned* cp = csb + (size_t)k * N_ + qt * 64 + c0;
    #pragma unroll
    for (int i = 0; i < 16; i += 4){
      float4 bv = *(const float4*)(bp + i);
      float b4[4] = { bv.x, bv.y, bv.z, bv.w };
      float cB[4], sB[4];
      unsigned o[4];
      #pragma unroll
      for (int j = 0; j < 4; j++){
        float Br = (b4[j] + 180.f) * 0.017453292519943295f;
        __sincosf(Br, &sB[j], &cB[j]);
        o[j] = ((unsigned)(unsigned short)f2bf(cB[j])) |
               (((unsigned)(unsigned short)f2bf(sB[j])) << 16);
      }
      *(uint4*)(cp + i) = make_uint4(o[0], o[1], o[2], o[3]);
      if (do_align){
        #pragma unroll
        for (int b = 0; b < 8; b++){
          unsigned w2[2];
          #pragma unroll
          for (int p = 0; p < 2; p++){
            unsigned lo = 0, hi = 0;
            #pragma unroll
            for (int j = 0; j < 2; j++){
              int q = c0 + i + p * 2 + j;
              float al = fmaf(cA_[b][q], cB[p * 2 + j], sA_[b][q] * sB[p * 2 + j]);
              unsigned v = (unsigned)(unsigned short)f2bf(al);
              if (j == 0) lo = v; else hi = v;
            }
            w2[p] = lo | (hi << 16);
          }
          *(uint2*)(alignT + ((size_t)b * N_ + k) * N_ + qt * 64 + c0 + i) =
              make_uint2(w2[0], w2[1]);
        }
      }
    }
  }

  // adjT via LDS transpose
  {
    int k = kt * 64 + r;
    short* op = adjT + (size_t)k * N_ + qt * 64 + c0;
    bf16x8 v0, v1;
    #pragma unroll
    for (int j = 0; j < 8; j++){ v0[j] = tt[c0 + j][r]; v1[j] = tt[c0 + 8 + j][r]; }
    *(bf16x8*)op = v0;
    *(bf16x8*)(op + 8) = v1;
  }
}

// ---------------- MFMA GEMM: C[M x N] = A[M x K] * Bt[N x K]^T ----------------
__global__ __launch_bounds__(256) void gemm_bt(const short* __restrict__ A,
                                               const short* __restrict__ Bt,
                                               short* __restrict__ C,
                                               float* __restrict__ Cf,
                                               const float* __restrict__ residf,
                                               int N, int rope)
{
  const int K = D_;
  __shared__ short As[128 * 32];
  __shared__ short Bs[128 * 32];
  int tid  = threadIdx.x;
  int wave = tid >> 6;
  int lane = tid & 63;
  int quad = lane >> 4;
  int l16  = lane & 15;
  int wr = wave >> 1, wc = wave & 1;
  int m0 = blockIdx.x * 128;
  int n0 = blockIdx.y * 128;

  f32x4 acc[4][4];
  #pragma unroll
  for (int i = 0; i < 4; i++)
    #pragma unroll
    for (int j = 0; j < 4; j++)
      acc[i][j] = (f32x4){0.f, 0.f, 0.f, 0.f};

  for (int k0 = 0; k0 < K; k0 += 32){
    __syncthreads();
    #pragma unroll
    for (int it = 0; it < 2; ++it){
      int c   = tid + it * 256;
      int row = c >> 2;
      int cc  = c & 3;
      const short* ga = A  + (size_t)(m0 + row) * K + k0 + cc * 8;
      const short* gb = Bt + (size_t)(n0 + row) * K + k0 + cc * 8;
      short* la = As + (size_t)(wave * 64 + it * 256) * 8;
      short* lb = Bs + (size_t)(wave * 64 + it * 256) * 8;
      __builtin_amdgcn_global_load_lds((const __attribute__((address_space(1))) void*)ga,
                                       (__attribute__((address_space(3))) void*)la, 16, 0, 0);
      __builtin_amdgcn_global_load_lds((const __attribute__((address_space(1))) void*)gb,
                                       (__attribute__((address_space(3))) void*)lb, 16, 0, 0);
    }
    __syncthreads();

    bf16x8 af[4], bfr[4];
    #pragma unroll
    for (int i = 0; i < 4; i++)
      af[i] = *(const bf16x8*)(As + (size_t)(wr * 64 + i * 16 + l16) * 32 + quad * 8);
    #pragma unroll
    for (int j = 0; j < 4; j++)
      bfr[j] = *(const bf16x8*)(Bs + (size_t)(wc * 64 + j * 16 + l16) * 32 + quad * 8);
    #pragma unroll
    for (int i = 0; i < 4; i++)
      #pragma unroll
      for (int j = 0; j < 4; j++)
        acc[i][j] = __builtin_amdgcn_mfma_f32_16x16x32_bf16(af[i], bfr[j], acc[i][j], 0, 0, 0);
  }

  if (rope){
    int cb  = n0 + wc * 64;            // head base col (64-aligned)
    int mat = cb / D_;                 // 0=Q, 1=K, 2=V
    if (mat < 2){
      float scale = (mat == 0) ? QSCALE_ : 1.0f;
      float invf0 = exp2f(-0.4152410118609203f * (float)l16);  // 10000^(-l16/32)
      float invf1 = invf0 * 0.01f;                             // 10000^(-(16+l16)/32)
      #pragma unroll
      for (int i = 0; i < 4; i++){
        #pragma unroll
        for (int rr = 0; rr < 4; rr++){
          int r = m0 + wr * 64 + i * 16 + quad * 4 + rr;
          float nseq = (float)(r & (N_ - 1));
          float s0, c0v, s1, c1v;
          __sincosf(nseq * invf0, &s0, &c0v);
          __sincosf(nseq * invf1, &s1, &c1v);
          float x1 = acc[i][0][rr], x2 = acc[i][2][rr];
          acc[i][0][rr] = (x1 * c0v - x2 * s0) * scale;
          acc[i][2][rr] = (x2 * c0v + x1 * s0) * scale;
          x1 = acc[i][1][rr]; x2 = acc[i][3][rr];
          acc[i][1][rr] = (x1 * c1v - x2 * s1) * scale;
          acc[i][3][rr] = (x2 * c1v + x1 * s1) * scale;
        }
      }
    }
  }

  #pragma unroll
  for (int i = 0; i < 4; i++){
    #pragma unroll
    for (int rr = 0; rr < 4; rr++){
      int r = m0 + wr * 64 + i * 16 + quad * 4 + rr;
      size_t rowoff = (size_t)r * N;
      #pragma unroll
      for (int j = 0; j < 4; j++){
        int cidx = n0 + wc * 64 + j * 16 + l16;
        float v = acc[i][j][rr];
        if (Cf){
          Cf[rowoff + cidx] = v + residf[rowoff + cidx];
        } else {
          C[rowoff + cidx] = f2bf(v);
        }
      }
    }
  }
}

// ---------------- MFMA flash attention, fixed-max softmax, exp2 domain ----------------
// r2 counters: VALU 41% + LDS-pipe ~42% + MFMA 8%, and wall == their SUM -> the
// phases run chip-wide in lockstep (all waves in the same phase). Fixes:
//  * intra-wave interleave: bias(jc=0,1) -> PV(kc=0) -> bias(jc=2,3) -> PV(kc=1)
//    so each wave alternates VALU/LDS at ~600-cyc granularity (pipes overlap);
//  * v_cvt_pk_bf16_f32 for P-writes (1 op / 2 elems vs 4 ops/elem, same RNE);
//  * XCD-locality: bid = qt*112 + hh*8 + b -> bid%8 == b, so each XCD's L2 holds
//    ONE batch's K/V (3.5 MB < 4 MB L2) + its alignT rows;
//  * tile stagger kt0 = qt*2: sibling blocks start on different K-tiles
//    (fixed-max softmax is k-order-invariant) -> cooperative L2 fill.
// VGPR must stay <= 64 (4 blocks/CU); loop spill at (512,6) -- do not tighten.
template<int PRE>
__global__ __launch_bounds__(512, 4) void attn_kernel(
    const short* __restrict__ QKV,
    const unsigned* __restrict__ csb,   // [k][q] packed (cosB lo16, sinB hi16)  (PRE=0)
    const short* __restrict__ adjT,     // [k][q] bf16
    const short* __restrict__ alignT,   // [b][k][q] bf16                         (PRE=1)
    const float* __restrict__ wind_dirs,
    const float* __restrict__ wind_w,
    const float* __restrict__ wind_b,
    short* __restrict__ outb)
{
  __shared__ short K_s[64 * 72];       // K[k][d]
  __shared__ short V_t[64 * 76];       // V^T[d][k]
  __shared__ short P_s[128 * 76];      // P[q][k]

  int bid = blockIdx.x;
  // bid = qt*112 + hh*8 + b  (112%8==0 -> XCD = bid%8 = b)
  int qt  = bid / 112;
  int rem = bid - qt * 112;
  int hh  = rem >> 3;
  int b   = rem & 7;
  int q0  = qt * 128;
  int kt0 = (qt * 2) & 15;             // staggered starting K-tile

  int t    = threadIdx.x;
  int w    = t >> 6;          // 0..7
  int lane = t & 63;
  int quad = lane >> 4;
  int l16  = lane & 15;

  // Q fragments (A-operand): m = l16 (q row in wave), k = kc*32 + quad*8 + j
  const short* qp = QKV + ((size_t)(b * N_) + q0 + w * 16 + l16) * DQKV_ + hh * DH_;
  bf16x8 qf0 = *(const bf16x8*)(qp + quad * 8);
  bf16x8 qf1 = *(const bf16x8*)(qp + 32 + quad * 8);

  // wind dir trig per q-row -- only needed when align is computed inline
  float cA[4], sA[4];
  if (!PRE){
    #pragma unroll
    for (int rr = 0; rr < 4; rr++){
      float wd = wind_dirs[(size_t)b * N_ + q0 + w * 16 + quad * 4 + rr];
      float A  = wd * 0.017453292519943295f;
      sA[rr] = __sinf(A);
      cA[rr] = __cosf(A);
    }
  }
  // weights pre-scaled by 2*log2e so e^{2z} = exp2(z2) with no extra multiply
  float w0m = wind_w[hh]      * TWO_LOG2E_;
  float w1m = wind_w[H_ + hh] * TWO_LOG2E_;
  float wbm = wind_b[hh]      * TWO_LOG2E_;

  float l[4] = {0.f, 0.f, 0.f, 0.f};
  f32x4 O[4];
  #pragma unroll
  for (int dc = 0; dc < 4; dc++) O[dc] = (f32x4){0.f, 0.f, 0.f, 0.f};

  // staging indices
  int kr  = t >> 3, kc8 = (t & 7) * 8;          // K rows (1 bf16x8 per thread)
  int vk2 = (t >> 4) * 2, vd4 = (t & 15) * 4;   // V: 2 k-rows x 4 d per thread
  const short* kg0 = QKV + ((size_t)(b * N_) + kr)  * DQKV_ + D_     + hh * DH_ + kc8;
  const short* vg0 = QKV + ((size_t)(b * N_) + vk2) * DQKV_ + 2 * D_ + hh * DH_ + vd4;

  int k0f = kt0 * 64;
  // prologue prefetch (tile kt0): K/V
  bf16x8 pk  = *(const bf16x8*)(kg0 + (size_t)k0f * DQKV_);
  bf16x4 pv0 = *(const bf16x4*)(vg0 + (size_t)k0f * DQKV_);
  bf16x4 pv1 = *(const bf16x4*)(vg0 + (size_t)(k0f + 1) * DQKV_);

  // prologue prefetch (tile kt0): bias inputs
  size_t bias_q = (size_t)(q0 + w * 16 + quad * 4);
  u32x4 cs4a[4]; bf16x4 al4a[4]; bf16x4 av4a[4];
  #pragma unroll
  for (int jc = 0; jc < 4; jc++){
    size_t off = (size_t)(k0f + jc * 16 + l16) * N_ + bias_q;
    if (PRE) al4a[jc] = *(const bf16x4*)(alignT + (size_t)b * N_ * N_ + off);
    else     cs4a[jc] = *(const u32x4*)(csb + off);
    av4a[jc] = *(const bf16x4*)(adjT + off);
  }

  for (int it = 0; it < 16; ++it){
    int ktn = (it + 1 + kt0) & 15;     // next tile (wraps harmlessly on last iter)
    int kn  = ktn * 64;

    BAR_LDS();                         // prev tile's LDS reads all consumed; WAR-safe
    *(bf16x8*)(K_s + kr * 72 + kc8) = pk;
    #pragma unroll
    for (int j = 0; j < 4; j++){
      unsigned pv = ((unsigned)(unsigned short)pv0[j]) |
                    (((unsigned)(unsigned short)pv1[j]) << 16);
      *(unsigned*)(V_t + (vd4 + j) * 76 + vk2) = pv;
    }
    BAR_LDS();                         // staging visible; vmcnt NOT drained

    // issue next tile's K/V prefetch -- in flight under the whole compute phase
    pk  = *(const bf16x8*)(kg0 + (size_t)kn * DQKV_);
    pv0 = *(const bf16x4*)(vg0 + (size_t)kn * DQKV_);
    pv1 = *(const bf16x4*)(vg0 + (size_t)(kn + 1) * DQKV_);

    // S = Q K^T  (rows q, cols k) -- already in exp2 domain via Q scale
    f32x4 S[4];
    __builtin_amdgcn_s_setprio(1);
    #pragma unroll
    for (int jc = 0; jc < 4; jc++){
      S[jc] = (f32x4){0.f, 0.f, 0.f, 0.f};
      bf16x8 kf0 = *(const bf16x8*)(K_s + (jc * 16 + l16) * 72 + quad * 8);
      bf16x8 kf1 = *(const bf16x8*)(K_s + (jc * 16 + l16) * 72 + 32 + quad * 8);
      S[jc] = __builtin_amdgcn_mfma_f32_16x16x32_bf16(qf0, kf0, S[jc], 0, 0, 0);
      S[jc] = __builtin_amdgcn_mfma_f32_16x16x32_bf16(qf1, kf1, S[jc], 0, 0, 0);
    }
    __builtin_amdgcn_s_setprio(0);

    // ---- interleaved halves: bias(jc pair) then PV(kc) ----
    #pragma unroll
    for (int kc = 0; kc < 2; kc++){
      // bias + mask + exp2 for jc = 2kc, 2kc+1
      #pragma unroll
      for (int jc = kc * 2; jc < kc * 2 + 2; jc++){
        float ev[4];
        #pragma unroll
        for (int rr = 0; rr < 4; rr++){
          float av = bf2f(av4a[jc][rr]);
          float align;
          if (PRE){
            align = bf2f(al4a[jc][rr]);
          } else {
            unsigned u = cs4a[jc][rr];
            float cB = asf(u << 16);
            float sB = asf(u & 0xffff0000u);
            align = cA[rr] * cB + sA[rr] * sB;
          }
          float z2 = fmaf(align, w0m, fmaf(av, w1m, wbm));    // 2*log2e*z
          float e2 = __builtin_amdgcn_exp2f(z2);              // e^{2z}
          float rc = __builtin_amdgcn_rcpf(e2 + 1.f);
          float bias2 = fmaf(-TWO_LOG2E_, rc, BIAS_C_);       // log2e*(tanh(z) - M0)
          float sv = (av > 0.f ? S[jc][rr] : -1e30f) + bias2;
          float e = __builtin_amdgcn_exp2f(sv);
          l[rr] += e;
          ev[rr] = e;
        }
        unsigned pk01 = cvt_pk_bf16(ev[0], ev[1]);
        unsigned pk23 = cvt_pk_bf16(ev[2], ev[3]);
        short* pb = P_s + (w * 16 + quad * 4) * 76 + jc * 16 + l16;
        pb[0]   = (short)pk01;
        pb[76]  = (short)(pk01 >> 16);
        pb[152] = (short)pk23;
        pb[228] = (short)(pk23 >> 16);
      }

      // PV for this kc half (A-layout read of own P rows)
      __builtin_amdgcn_s_setprio(1);
      {
        const short* pp = P_s + (w * 16 + l16) * 76 + kc * 32 + quad * 8;
        bf16x4 p0 = *(const bf16x4*)pp;
        bf16x4 p1 = *(const bf16x4*)(pp + 4);
        bf16x8 pf = { p0[0], p0[1], p0[2], p0[3], p1[0], p1[1], p1[2], p1[3] };
        #pragma unroll
        for (int dc = 0; dc < 4; dc++){
          const short* vp = V_t + (dc * 16 + l16) * 76 + kc * 32 + quad * 8;
          bf16x4 u0 = *(const bf16x4*)vp;
          bf16x4 u1 = *(const bf16x4*)(vp + 4);
          bf16x8 vf = { u0[0], u0[1], u0[2], u0[3], u1[0], u1[1], u1[2], u1[3] };
          O[dc] = __builtin_amdgcn_mfma_f32_16x16x32_bf16(pf, vf, O[dc], 0, 0, 0);
        }
      }
      __builtin_amdgcn_s_setprio(0);

      // prefetch next tile's bias inputs for the jc-pair just consumed
      #pragma unroll
      for (int jc = kc * 2; jc < kc * 2 + 2; jc++){
        size_t off = (size_t)(kn + jc * 16 + l16) * N_ + bias_q;
        if (PRE) al4a[jc] = *(const bf16x4*)(alignT + (size_t)b * N_ * N_ + off);
        else     cs4a[jc] = *(const u32x4*)(csb + off);
        av4a[jc] = *(const bf16x4*)(adjT + off);
      }
    }
  }

  // epilogue: reduce l across the 16 lanes of the row group, O / l, write bf16
  float rl[4];
  #pragma unroll
  for (int rr = 0; rr < 4; rr++){
    float rs = l[rr];
    rs += __shfl_xor(rs, 1);
    rs += __shfl_xor(rs, 2);
    rs += __shfl_xor(rs, 4);
    rs += __shfl_xor(rs, 8);
    rl[rr] = 1.f / rs;
  }
  short* op = outb + ((size_t)(b * N_) + q0 + w * 16) * D_ + hh * DH_;
  #pragma unroll
  for (int rr = 0; rr < 4; rr++)
    #pragma unroll
    for (int dc = 0; dc < 4; dc++)
      op[(size_t)(quad * 4 + rr) * D_ + dc * 16 + l16] = f2bf(O[dc][rr] * rl[rr]);
}

extern "C" void kernel_launch(void* const* d_in, const int* in_sizes, int n_in,
                              void* d_out, int out_size, void* d_ws, size_t ws_size,
                              hipStream_t stream)
{
  const float* nf   = (const float*)d_in[0];
  const float* adj  = (const float*)d_in[1];
  const float* wdir = (const float*)d_in[2];
  const float* brg  = (const float*)d_in[3];
  const float* Wq   = (const float*)d_in[4];
  const float* Wk   = (const float*)d_in[5];
  const float* Wv   = (const float*)d_in[6];
  const float* Wo   = (const float*)d_in[7];
  const float* lng  = (const float*)d_in[8];
  const float* lnb  = (const float*)d_in[9];
  const float* ww   = (const float*)d_in[10];
  const float* wbb  = (const float*)d_in[11];
  float* out = (float*)d_out;

  short* base = (short*)d_ws;
  size_t sh = 0;
  short* xln   = base + sh;  sh += (size_t)M_ * D_;        // reused as attn out
  short* WqkvT = base + sh;  sh += (size_t)DQKV_ * D_;
  short* WoT   = base + sh;  sh += (size_t)D_ * D_;
  short* QKV   = base + sh;  sh += (size_t)M_ * DQKV_;
  unsigned* csb = (unsigned*)(base + sh); sh += (size_t)N_ * N_ * 2;  // u32 = 2 shorts
  short* adjT  = base + sh;  sh += (size_t)N_ * N_;
  short* alignT = base + sh; sh += (size_t)B_ * N_ * N_;
  size_t need_pre = sh * sizeof(short);
  bool pre = (ws_size >= need_pre);

  ln_kernel<<<M_, 256, 0, stream>>>(nf, lng, lnb, xln);
  transpose_kernel<<<dim3(14, 14, 4), 256, 0, stream>>>(Wq, Wk, Wv, Wo, WqkvT, WoT);
  prep_kernel<<<dim3(16, 16), 256, 0, stream>>>(adj, brg, wdir, csb, adjT, alignT, pre ? 1 : 0);
  gemm_bt<<<dim3(M_ / 128, DQKV_ / 128), 256, 0, stream>>>(xln, WqkvT, QKV, nullptr, nullptr, DQKV_, 1);
  if (pre)
    attn_kernel<1><<<B_ * H_ * 8, 512, 0, stream>>>(QKV, csb, adjT, alignT, wdir, ww, wbb, xln);
  else
    attn_kernel<0><<<B_ * H_ * 8, 512, 0, stream>>>(QKV, csb, adjT, alignT, wdir, ww, wbb, xln);
  gemm_bt<<<dim3(M_ / 128, D_ / 128), 256, 0, stream>>>(xln, WoT, nullptr, out, nf, D_, 0);
}

// Round 4
// 371.313 us; speedup vs baseline: 1.0926x; 1.0352x over previous
//
#include <hip/hip_runtime.h>
#include <hip/hip_bf16.h>
#include <math.h>

#define B_ 8
#define N_ 1024
#define H_ 14
#define DH_ 64
#define D_ 896
#define M_ (B_*N_)        // 8192 rows
#define DQKV_ 2688        // 3*D_

// exp2-domain constants: 2*log2(e), log2(e)*(1 - M0) with M0 = 12
#define TWO_LOG2E_ 2.8853900817779268f
#define BIAS_C_   (-15.869645449778597f)
#define QSCALE_     0.18033688011112043f   // 0.125 * log2(e), folded into Q at GEMM epilogue

typedef __attribute__((ext_vector_type(8))) short bf16x8;
typedef __attribute__((ext_vector_type(4))) short bf16x4;
typedef __attribute__((ext_vector_type(4))) float f32x4;
typedef __attribute__((ext_vector_type(4))) unsigned u32x4;

__device__ __forceinline__ float bf2f(short s){
  unsigned u = ((unsigned)(unsigned short)s) << 16;
  union { unsigned u; float f; } c; c.u = u; return c.f;
}
__device__ __forceinline__ short f2bf(float f){
  union { float f; unsigned u; } c; c.f = f;
  unsigned u = c.u;
  unsigned r = (u + 0x7FFFu + ((u >> 16) & 1u)) >> 16;
  return (short)(unsigned short)r;
}
__device__ __forceinline__ float asf(unsigned u){
  union { unsigned u; float f; } c; c.u = u; return c.f;
}
// pack 2 f32 -> 2 bf16 in one VALU op (RNE -- bit-identical to f2bf above)
__device__ __forceinline__ unsigned cvt_pk_bf16(float lo, float hi){
  unsigned r;
  asm("v_cvt_pk_bf16_f32 %0, %1, %2" : "=v"(r) : "v"(lo), "v"(hi));
  return r;
}

// raw workgroup barrier: LDS visibility only (lgkm), does NOT drain vmcnt ->
// global register-prefetches stay in flight across it (T14/T4-lite).
#define BAR_LDS() do { asm volatile("s_waitcnt lgkmcnt(0)" ::: "memory"); \
                       __builtin_amdgcn_s_barrier(); } while (0)

// ---------------- LayerNorm: one block per row, f32 in -> bf16 out ----------------
__global__ __launch_bounds__(256) void ln_kernel(const float* __restrict__ x,
                                                 const float* __restrict__ g,
                                                 const float* __restrict__ bb,
                                                 short* __restrict__ y)
{
  int row = blockIdx.x;
  const float* xr = x + (size_t)row * D_;
  float s = 0.f, s2 = 0.f;
  for (int i = threadIdx.x; i < D_; i += 256){
    float v = xr[i]; s += v; s2 = fmaf(v, v, s2);
  }
  #pragma unroll
  for (int off = 32; off > 0; off >>= 1){
    s  += __shfl_down(s,  off, 64);
    s2 += __shfl_down(s2, off, 64);
  }
  __shared__ float rs_[4], rs2_[4];
  int wv = threadIdx.x >> 6;
  if ((threadIdx.x & 63) == 0){ rs_[wv] = s; rs2_[wv] = s2; }
  __syncthreads();
  float ts  = rs_[0] + rs_[1] + rs_[2] + rs_[3];
  float ts2 = rs2_[0] + rs2_[1] + rs2_[2] + rs2_[3];
  float mu  = ts * (1.f / D_);
  float var = ts2 * (1.f / D_) - mu * mu;
  float rstd = rsqrtf(var + 1e-5f);
  short* yr = y + (size_t)row * D_;
  for (int i = threadIdx.x; i < D_; i += 256){
    yr[i] = f2bf((xr[i] - mu) * rstd * g[i] + bb[i]);
  }
}

// ---------------- Transpose weights: f32 W[k][n] -> bf16 Wt[n][k] ----------------
__global__ __launch_bounds__(256) void transpose_kernel(
    const float* __restrict__ Wq, const float* __restrict__ Wk,
    const float* __restrict__ Wv, const float* __restrict__ Wo,
    short* __restrict__ WqkvT, short* __restrict__ WoT)
{
  __shared__ short t[64][72];
  int z = blockIdx.z;
  const float* W = (z == 0) ? Wq : (z == 1) ? Wk : (z == 2) ? Wv : Wo;
  int kb = blockIdx.x * 64, nb = blockIdx.y * 64;
  int c0 = (threadIdx.x & 7) * 8;
  int r0 = threadIdx.x >> 3;            // 0..31
  #pragma unroll
  for (int rr = 0; rr < 64; rr += 32){
    const float* src = &W[(size_t)(kb + r0 + rr) * D_ + nb + c0];
    float4 a = *(const float4*)src;
    float4 b = *(const float4*)(src + 4);
    short* dstl = &t[r0 + rr][c0];
    dstl[0] = f2bf(a.x); dstl[1] = f2bf(a.y); dstl[2] = f2bf(a.z); dstl[3] = f2bf(a.w);
    dstl[4] = f2bf(b.x); dstl[5] = f2bf(b.y); dstl[6] = f2bf(b.z); dstl[7] = f2bf(b.w);
  }
  __syncthreads();
  short* dst = (z < 3) ? (WqkvT + (size_t)(z * D_) * D_) : WoT;
  #pragma unroll
  for (int rr = 0; rr < 64; rr += 32){
    int n = nb + r0 + rr;
    bf16x8 v;
    #pragma unroll
    for (int j = 0; j < 8; j++) v[j] = t[c0 + j][r0 + rr];
    *(bf16x8*)&dst[(size_t)n * D_ + kb + c0] = v;
  }
}

// ---------------- Prep: adjT[k][q]; csb[k][q] (PRE=0) OR alignT[b][k][q] (PRE=1) ----
// Coalesced alignT: all 16 trig values computed first, then per-batch 2x uint4
// (32B/lane, 4 lanes = full 128B lines). csb skipped when do_align (never read).
__global__ __launch_bounds__(256) void prep_kernel(
    const float* __restrict__ adj, const float* __restrict__ brg,
    const float* __restrict__ wdir,
    unsigned* __restrict__ csb, short* __restrict__ adjT,
    short* __restrict__ alignT, int do_align)
{
  int kt = blockIdx.x, qt = blockIdx.y;
  __shared__ short tt[64][72];
  __shared__ float cA_[8][64], sA_[8][64];

  if (do_align){
    for (int idx = threadIdx.x; idx < 8 * 64; idx += 256){
      int b = idx >> 6, q = idx & 63;
      float A = wdir[(size_t)b * N_ + qt * 64 + q] * 0.017453292519943295f;
      float s, c; __sincosf(A, &s, &c);
      sA_[b][q] = s; cA_[b][q] = c;
    }
  }

  int r  = threadIdx.x >> 2;          // 0..63
  int c0 = (threadIdx.x & 3) * 16;    // 0..48

  // adj -> tt staging (for adjT transpose)
  {
    int q = qt * 64 + r;
    const float* ap = adj + (size_t)q * N_ + kt * 64 + c0;
    #pragma unroll
    for (int i = 0; i < 16; i += 4){
      float4 av = *(const float4*)(ap + i);
      tt[r][c0 + i]     = f2bf(av.x);
      tt[r][c0 + i + 1] = f2bf(av.y);
      tt[r][c0 + i + 2] = f2bf(av.z);
      tt[r][c0 + i + 3] = f2bf(av.w);
    }
  }
  __syncthreads();   // covers both cA_/sA_ and tt

  int k = kt * 64 + r;
  // bearing trig for this thread's 16 q's
  float cB[16], sB[16];
  {
    const float* bp = brg + (size_t)k * N_ + qt * 64 + c0;
    #pragma unroll
    for (int i = 0; i < 16; i += 4){
      float4 bv = *(const float4*)(bp + i);
      float b4[4] = { bv.x, bv.y, bv.z, bv.w };
      #pragma unroll
      for (int j = 0; j < 4; j++){
        float Br = (b4[j] + 180.f) * 0.017453292519943295f;
        __sincosf(Br, &sB[i + j], &cB[i + j]);
      }
    }
  }

  if (do_align){
    #pragma unroll
    for (int b = 0; b < 8; b++){
      unsigned w8[8];
      #pragma unroll
      for (int p = 0; p < 8; p++){
        int q0i = c0 + 2 * p, q1i = q0i + 1;
        float a0 = fmaf(cA_[b][q0i], cB[2 * p],     sA_[b][q0i] * sB[2 * p]);
        float a1 = fmaf(cA_[b][q1i], cB[2 * p + 1], sA_[b][q1i] * sB[2 * p + 1]);
        w8[p] = cvt_pk_bf16(a0, a1);
      }
      short* dst = alignT + ((size_t)b * N_ + k) * N_ + qt * 64 + c0;
      *(uint4*)dst       = make_uint4(w8[0], w8[1], w8[2], w8[3]);
      *(uint4*)(dst + 8) = make_uint4(w8[4], w8[5], w8[6], w8[7]);
    }
  } else {
    unsigned* cp = csb + (size_t)k * N_ + qt * 64 + c0;
    #pragma unroll
    for (int i = 0; i < 16; i += 4){
      unsigned o[4];
      #pragma unroll
      for (int j = 0; j < 4; j++)
        o[j] = ((unsigned)(unsigned short)f2bf(cB[i + j])) |
               (((unsigned)(unsigned short)f2bf(sB[i + j])) << 16);
      *(uint4*)(cp + i) = make_uint4(o[0], o[1], o[2], o[3]);
    }
  }

  // adjT via LDS transpose
  {
    short* op = adjT + (size_t)k * N_ + qt * 64 + c0;
    bf16x8 v0, v1;
    #pragma unroll
    for (int j = 0; j < 8; j++){ v0[j] = tt[c0 + j][r]; v1[j] = tt[c0 + 8 + j][r]; }
    *(bf16x8*)op = v0;
    *(bf16x8*)(op + 8) = v1;
  }
}

// ---------------- MFMA GEMM: C[M x N] = A[M x K] * Bt[N x K]^T ----------------
__global__ __launch_bounds__(256) void gemm_bt(const short* __restrict__ A,
                                               const short* __restrict__ Bt,
                                               short* __restrict__ C,
                                               float* __restrict__ Cf,
                                               const float* __restrict__ residf,
                                               int N, int rope)
{
  const int K = D_;
  __shared__ short As[128 * 32];
  __shared__ short Bs[128 * 32];
  int tid  = threadIdx.x;
  int wave = tid >> 6;
  int lane = tid & 63;
  int quad = lane >> 4;
  int l16  = lane & 15;
  int wr = wave >> 1, wc = wave & 1;
  int m0 = blockIdx.x * 128;
  int n0 = blockIdx.y * 128;

  f32x4 acc[4][4];
  #pragma unroll
  for (int i = 0; i < 4; i++)
    #pragma unroll
    for (int j = 0; j < 4; j++)
      acc[i][j] = (f32x4){0.f, 0.f, 0.f, 0.f};

  for (int k0 = 0; k0 < K; k0 += 32){
    __syncthreads();
    #pragma unroll
    for (int it = 0; it < 2; ++it){
      int c   = tid + it * 256;
      int row = c >> 2;
      int cc  = c & 3;
      const short* ga = A  + (size_t)(m0 + row) * K + k0 + cc * 8;
      const short* gb = Bt + (size_t)(n0 + row) * K + k0 + cc * 8;
      short* la = As + (size_t)(wave * 64 + it * 256) * 8;
      short* lb = Bs + (size_t)(wave * 64 + it * 256) * 8;
      __builtin_amdgcn_global_load_lds((const __attribute__((address_space(1))) void*)ga,
                                       (__attribute__((address_space(3))) void*)la, 16, 0, 0);
      __builtin_amdgcn_global_load_lds((const __attribute__((address_space(1))) void*)gb,
                                       (__attribute__((address_space(3))) void*)lb, 16, 0, 0);
    }
    __syncthreads();

    bf16x8 af[4], bfr[4];
    #pragma unroll
    for (int i = 0; i < 4; i++)
      af[i] = *(const bf16x8*)(As + (size_t)(wr * 64 + i * 16 + l16) * 32 + quad * 8);
    #pragma unroll
    for (int j = 0; j < 4; j++)
      bfr[j] = *(const bf16x8*)(Bs + (size_t)(wc * 64 + j * 16 + l16) * 32 + quad * 8);
    #pragma unroll
    for (int i = 0; i < 4; i++)
      #pragma unroll
      for (int j = 0; j < 4; j++)
        acc[i][j] = __builtin_amdgcn_mfma_f32_16x16x32_bf16(af[i], bfr[j], acc[i][j], 0, 0, 0);
  }

  if (rope){
    int cb  = n0 + wc * 64;            // head base col (64-aligned)
    int mat = cb / D_;                 // 0=Q, 1=K, 2=V
    if (mat < 2){
      float scale = (mat == 0) ? QSCALE_ : 1.0f;
      float invf0 = exp2f(-0.4152410118609203f * (float)l16);  // 10000^(-l16/32)
      float invf1 = invf0 * 0.01f;                             // 10000^(-(16+l16)/32)
      #pragma unroll
      for (int i = 0; i < 4; i++){
        #pragma unroll
        for (int rr = 0; rr < 4; rr++){
          int r = m0 + wr * 64 + i * 16 + quad * 4 + rr;
          float nseq = (float)(r & (N_ - 1));
          float s0, c0v, s1, c1v;
          __sincosf(nseq * invf0, &s0, &c0v);
          __sincosf(nseq * invf1, &s1, &c1v);
          float x1 = acc[i][0][rr], x2 = acc[i][2][rr];
          acc[i][0][rr] = (x1 * c0v - x2 * s0) * scale;
          acc[i][2][rr] = (x2 * c0v + x1 * s0) * scale;
          x1 = acc[i][1][rr]; x2 = acc[i][3][rr];
          acc[i][1][rr] = (x1 * c1v - x2 * s1) * scale;
          acc[i][3][rr] = (x2 * c1v + x1 * s1) * scale;
        }
      }
    }
  }

  #pragma unroll
  for (int i = 0; i < 4; i++){
    #pragma unroll
    for (int rr = 0; rr < 4; rr++){
      int r = m0 + wr * 64 + i * 16 + quad * 4 + rr;
      size_t rowoff = (size_t)r * N;
      #pragma unroll
      for (int j = 0; j < 4; j++){
        int cidx = n0 + wc * 64 + j * 16 + l16;
        float v = acc[i][j][rr];
        if (Cf){
          Cf[rowoff + cidx] = v + residf[rowoff + cidx];
        } else {
          C[rowoff + cidx] = f2bf(v);
        }
      }
    }
  }
}

// ---------------- MFMA flash attention, fixed-max softmax, exp2 domain ----------------
// r3 counters: FETCH halved (XCD swizzle) but dur flat; Occupancy 35% = ~11 waves/CU
// with a 896-block grid (3.5 blocks/CU) -> wave-supply limited, phases lockstep.
// This round: 64-q blocks, 4 waves, 256 threads -> grid 1792 (7 blocks/CU), LDS
// 28672 B (5 blocks/CU resident), barrier scope halved. Per-wave work unchanged;
// K/V staging duplicates (L2-resident, ~6 us of L2 BW).
template<int PRE>
__global__ __launch_bounds__(256, 4) void attn_kernel(
    const short* __restrict__ QKV,
    const unsigned* __restrict__ csb,   // [k][q] packed (cosB lo16, sinB hi16)  (PRE=0)
    const short* __restrict__ adjT,     // [k][q] bf16
    const short* __restrict__ alignT,   // [b][k][q] bf16                         (PRE=1)
    const float* __restrict__ wind_dirs,
    const float* __restrict__ wind_w,
    const float* __restrict__ wind_b,
    short* __restrict__ outb)
{
  __shared__ short K_s[64 * 72];       // K[k][d]
  __shared__ short V_t[64 * 76];       // V^T[d][k]
  __shared__ short P_s[64 * 76];       // P[q][k]

  int bid = blockIdx.x;
  // bid = qt*112 + hh*8 + b  (112%8==0 -> XCD = bid%8 = b)
  int qt  = bid / 112;                 // 0..15
  int rem = bid - qt * 112;
  int hh  = rem >> 3;
  int b   = rem & 7;
  int q0  = qt * 64;
  int kt0 = qt;                        // staggered starting K-tile (order-invariant)

  int t    = threadIdx.x;
  int w    = t >> 6;          // 0..3
  int lane = t & 63;
  int quad = lane >> 4;
  int l16  = lane & 15;

  // Q fragments (A-operand): m = l16 (q row in wave), k = kc*32 + quad*8 + j
  const short* qp = QKV + ((size_t)(b * N_) + q0 + w * 16 + l16) * DQKV_ + hh * DH_;
  bf16x8 qf0 = *(const bf16x8*)(qp + quad * 8);
  bf16x8 qf1 = *(const bf16x8*)(qp + 32 + quad * 8);

  // wind dir trig per q-row -- only needed when align is computed inline
  float cA[4], sA[4];
  if (!PRE){
    #pragma unroll
    for (int rr = 0; rr < 4; rr++){
      float wd = wind_dirs[(size_t)b * N_ + q0 + w * 16 + quad * 4 + rr];
      float A  = wd * 0.017453292519943295f;
      sA[rr] = __sinf(A);
      cA[rr] = __cosf(A);
    }
  }
  // weights pre-scaled by 2*log2e so e^{2z} = exp2(z2) with no extra multiply
  float w0m = wind_w[hh]      * TWO_LOG2E_;
  float w1m = wind_w[H_ + hh] * TWO_LOG2E_;
  float wbm = wind_b[hh]      * TWO_LOG2E_;

  float l[4] = {0.f, 0.f, 0.f, 0.f};
  f32x4 O[4];
  #pragma unroll
  for (int dc = 0; dc < 4; dc++) O[dc] = (f32x4){0.f, 0.f, 0.f, 0.f};

  // staging indices (256 threads)
  int kr   = t >> 2, kc16 = (t & 3) * 16;       // K: 1 row x 16 d per thread
  int vk4  = (t >> 4) * 4, vd4 = (t & 15) * 4;  // V: 4 k-rows x 4 d per thread
  const short* kg0 = QKV + ((size_t)(b * N_) + kr)  * DQKV_ + D_     + hh * DH_ + kc16;
  const short* vg0 = QKV + ((size_t)(b * N_) + vk4) * DQKV_ + 2 * D_ + hh * DH_ + vd4;

  int k0f = kt0 * 64;
  // prologue prefetch (tile kt0): K/V
  bf16x8 pk0 = *(const bf16x8*)(kg0 + (size_t)k0f * DQKV_);
  bf16x8 pk1 = *(const bf16x8*)(kg0 + (size_t)k0f * DQKV_ + 8);
  bf16x4 pv0 = *(const bf16x4*)(vg0 + (size_t)(k0f + 0) * DQKV_);
  bf16x4 pv1 = *(const bf16x4*)(vg0 + (size_t)(k0f + 1) * DQKV_);
  bf16x4 pv2 = *(const bf16x4*)(vg0 + (size_t)(k0f + 2) * DQKV_);
  bf16x4 pv3 = *(const bf16x4*)(vg0 + (size_t)(k0f + 3) * DQKV_);

  // prologue prefetch (tile kt0): bias inputs
  size_t bias_q = (size_t)(q0 + w * 16 + quad * 4);
  u32x4 cs4a[4]; bf16x4 al4a[4]; bf16x4 av4a[4];
  #pragma unroll
  for (int jc = 0; jc < 4; jc++){
    size_t off = (size_t)(k0f + jc * 16 + l16) * N_ + bias_q;
    if (PRE) al4a[jc] = *(const bf16x4*)(alignT + (size_t)b * N_ * N_ + off);
    else     cs4a[jc] = *(const u32x4*)(csb + off);
    av4a[jc] = *(const bf16x4*)(adjT + off);
  }

  for (int it = 0; it < 16; ++it){
    int ktn = (it + 1 + kt0) & 15;     // next tile (wraps harmlessly on last iter)
    int kn  = ktn * 64;

    BAR_LDS();                         // prev tile's LDS reads all consumed; WAR-safe
    *(bf16x8*)(K_s + kr * 72 + kc16)     = pk0;
    *(bf16x8*)(K_s + kr * 72 + kc16 + 8) = pk1;
    #pragma unroll
    for (int j = 0; j < 4; j++){
      unsigned lo = ((unsigned)(unsigned short)pv0[j]) |
                    (((unsigned)(unsigned short)pv1[j]) << 16);
      unsigned hi = ((unsigned)(unsigned short)pv2[j]) |
                    (((unsigned)(unsigned short)pv3[j]) << 16);
      *(uint2*)(V_t + (vd4 + j) * 76 + vk4) = make_uint2(lo, hi);
    }
    BAR_LDS();                         // staging visible; vmcnt NOT drained

    // issue next tile's K/V prefetch -- in flight under the whole compute phase
    pk0 = *(const bf16x8*)(kg0 + (size_t)kn * DQKV_);
    pk1 = *(const bf16x8*)(kg0 + (size_t)kn * DQKV_ + 8);
    pv0 = *(const bf16x4*)(vg0 + (size_t)(kn + 0) * DQKV_);
    pv1 = *(const bf16x4*)(vg0 + (size_t)(kn + 1) * DQKV_);
    pv2 = *(const bf16x4*)(vg0 + (size_t)(kn + 2) * DQKV_);
    pv3 = *(const bf16x4*)(vg0 + (size_t)(kn + 3) * DQKV_);

    // S = Q K^T  (rows q, cols k) -- already in exp2 domain via Q scale
    f32x4 S[4];
    __builtin_amdgcn_s_setprio(1);
    #pragma unroll
    for (int jc = 0; jc < 4; jc++){
      S[jc] = (f32x4){0.f, 0.f, 0.f, 0.f};
      bf16x8 kf0 = *(const bf16x8*)(K_s + (jc * 16 + l16) * 72 + quad * 8);
      bf16x8 kf1 = *(const bf16x8*)(K_s + (jc * 16 + l16) * 72 + 32 + quad * 8);
      S[jc] = __builtin_amdgcn_mfma_f32_16x16x32_bf16(qf0, kf0, S[jc], 0, 0, 0);
      S[jc] = __builtin_amdgcn_mfma_f32_16x16x32_bf16(qf1, kf1, S[jc], 0, 0, 0);
    }
    __builtin_amdgcn_s_setprio(0);

    // ---- interleaved halves: bias(jc pair) then PV(kc) ----
    #pragma unroll
    for (int kc = 0; kc < 2; kc++){
      // bias + mask + exp2 for jc = 2kc, 2kc+1
      #pragma unroll
      for (int jc = kc * 2; jc < kc * 2 + 2; jc++){
        float ev[4];
        #pragma unroll
        for (int rr = 0; rr < 4; rr++){
          float av = bf2f(av4a[jc][rr]);
          float align;
          if (PRE){
            align = bf2f(al4a[jc][rr]);
          } else {
            unsigned u = cs4a[jc][rr];
            float cB = asf(u << 16);
            float sB = asf(u & 0xffff0000u);
            align = cA[rr] * cB + sA[rr] * sB;
          }
          float z2 = fmaf(align, w0m, fmaf(av, w1m, wbm));    // 2*log2e*z
          float e2 = __builtin_amdgcn_exp2f(z2);              // e^{2z}
          float rc = __builtin_amdgcn_rcpf(e2 + 1.f);
          float bias2 = fmaf(-TWO_LOG2E_, rc, BIAS_C_);       // log2e*(tanh(z) - M0)
          float sv = (av > 0.f ? S[jc][rr] : -1e30f) + bias2;
          float e = __builtin_amdgcn_exp2f(sv);
          l[rr] += e;
          ev[rr] = e;
        }
        unsigned pk01 = cvt_pk_bf16(ev[0], ev[1]);
        unsigned pk23 = cvt_pk_bf16(ev[2], ev[3]);
        short* pb = P_s + (w * 16 + quad * 4) * 76 + jc * 16 + l16;
        pb[0]   = (short)pk01;
        pb[76]  = (short)(pk01 >> 16);
        pb[152] = (short)pk23;
        pb[228] = (short)(pk23 >> 16);
      }

      // PV for this kc half (A-layout read of own P rows)
      __builtin_amdgcn_s_setprio(1);
      {
        const short* pp = P_s + (w * 16 + l16) * 76 + kc * 32 + quad * 8;
        bf16x4 p0 = *(const bf16x4*)pp;
        bf16x4 p1 = *(const bf16x4*)(pp + 4);
        bf16x8 pf = { p0[0], p0[1], p0[2], p0[3], p1[0], p1[1], p1[2], p1[3] };
        #pragma unroll
        for (int dc = 0; dc < 4; dc++){
          const short* vp = V_t + (dc * 16 + l16) * 76 + kc * 32 + quad * 8;
          bf16x4 u0 = *(const bf16x4*)vp;
          bf16x4 u1 = *(const bf16x4*)(vp + 4);
          bf16x8 vf = { u0[0], u0[1], u0[2], u0[3], u1[0], u1[1], u1[2], u1[3] };
          O[dc] = __builtin_amdgcn_mfma_f32_16x16x32_bf16(pf, vf, O[dc], 0, 0, 0);
        }
      }
      __builtin_amdgcn_s_setprio(0);

      // prefetch next tile's bias inputs for the jc-pair just consumed
      #pragma unroll
      for (int jc = kc * 2; jc < kc * 2 + 2; jc++){
        size_t off = (size_t)(kn + jc * 16 + l16) * N_ + bias_q;
        if (PRE) al4a[jc] = *(const bf16x4*)(alignT + (size_t)b * N_ * N_ + off);
        else     cs4a[jc] = *(const u32x4*)(csb + off);
        av4a[jc] = *(const bf16x4*)(adjT + off);
      }
    }
  }

  // epilogue: reduce l across the 16 lanes of the row group, O / l, write bf16
  float rl[4];
  #pragma unroll
  for (int rr = 0; rr < 4; rr++){
    float rs = l[rr];
    rs += __shfl_xor(rs, 1);
    rs += __shfl_xor(rs, 2);
    rs += __shfl_xor(rs, 4);
    rs += __shfl_xor(rs, 8);
    rl[rr] = 1.f / rs;
  }
  short* op = outb + ((size_t)(b * N_) + q0 + w * 16) * D_ + hh * DH_;
  #pragma unroll
  for (int rr = 0; rr < 4; rr++)
    #pragma unroll
    for (int dc = 0; dc < 4; dc++)
      op[(size_t)(quad * 4 + rr) * D_ + dc * 16 + l16] = f2bf(O[dc][rr] * rl[rr]);
}

extern "C" void kernel_launch(void* const* d_in, const int* in_sizes, int n_in,
                              void* d_out, int out_size, void* d_ws, size_t ws_size,
                              hipStream_t stream)
{
  const float* nf   = (const float*)d_in[0];
  const float* adj  = (const float*)d_in[1];
  const float* wdir = (const float*)d_in[2];
  const float* brg  = (const float*)d_in[3];
  const float* Wq   = (const float*)d_in[4];
  const float* Wk   = (const float*)d_in[5];
  const float* Wv   = (const float*)d_in[6];
  const float* Wo   = (const float*)d_in[7];
  const float* lng  = (const float*)d_in[8];
  const float* lnb  = (const float*)d_in[9];
  const float* ww   = (const float*)d_in[10];
  const float* wbb  = (const float*)d_in[11];
  float* out = (float*)d_out;

  short* base = (short*)d_ws;
  size_t sh = 0;
  short* xln   = base + sh;  sh += (size_t)M_ * D_;        // reused as attn out
  short* WqkvT = base + sh;  sh += (size_t)DQKV_ * D_;
  short* WoT   = base + sh;  sh += (size_t)D_ * D_;
  short* QKV   = base + sh;  sh += (size_t)M_ * DQKV_;
  unsigned* csb = (unsigned*)(base + sh); sh += (size_t)N_ * N_ * 2;  // u32 = 2 shorts
  short* adjT  = base + sh;  sh += (size_t)N_ * N_;
  short* alignT = base + sh; sh += (size_t)B_ * N_ * N_;
  size_t need_pre = sh * sizeof(short);
  bool pre = (ws_size >= need_pre);

  ln_kernel<<<M_, 256, 0, stream>>>(nf, lng, lnb, xln);
  transpose_kernel<<<dim3(14, 14, 4), 256, 0, stream>>>(Wq, Wk, Wv, Wo, WqkvT, WoT);
  prep_kernel<<<dim3(16, 16), 256, 0, stream>>>(adj, brg, wdir, csb, adjT, alignT, pre ? 1 : 0);
  gemm_bt<<<dim3(M_ / 128, DQKV_ / 128), 256, 0, stream>>>(xln, WqkvT, QKV, nullptr, nullptr, DQKV_, 1);
  if (pre)
    attn_kernel<1><<<B_ * H_ * 16, 256, 0, stream>>>(QKV, csb, adjT, alignT, wdir, ww, wbb, xln);
  else
    attn_kernel<0><<<B_ * H_ * 16, 256, 0, stream>>>(QKV, csb, adjT, alignT, wdir, ww, wbb, xln);
  gemm_bt<<<dim3(M_ / 128, D_ / 128), 256, 0, stream>>>(xln, WoT, nullptr, out, nf, D_, 0);
}